// Round 1
// baseline (1110.526 us; speedup 1.0000x reference)
//
#include <hip/hip_runtime.h>
#include <hip/hip_bf16.h>

// Problem: B=2, S=2048, D=2048, H=16, HD=128, causal MHA with 4 linear proj.
// Pipeline: 3x GEMM (fp32 in -> bf16 out) -> flash attention (bf16) -> GEMM (bf16 in -> fp32 out)

#define LOG2E 1.44269504088896340736f

typedef __attribute__((ext_vector_type(8))) short short8;   // 8 x bf16 (4 VGPRs)
typedef __attribute__((ext_vector_type(4))) float floatx4;  // MFMA acc

__device__ __forceinline__ short f2bf(float f) {
  unsigned int u = __builtin_bit_cast(unsigned int, f);
  u += 0x7FFFu + ((u >> 16) & 1u);  // RNE
  return (short)(u >> 16);
}

// C[M][N] = A[M][K] * Bt[N][K]^T + bias[N]
// A: fp32 or bf16 (A_BF16). Bt: fp32 (weights, converted on the fly). Out: bf16 or fp32.
// Block: 256 thr, tile 128x128, BK=32. Wave (wr,wc) computes 64x64 as 4x4 MFMA 16x16 tiles.
template<bool A_BF16, bool OUT_BF16>
__global__ __launch_bounds__(256, 2) void gemm_bias_k(
    const void* __restrict__ Aptr, const float* __restrict__ Bt,
    const float* __restrict__ bias, void* __restrict__ Cptr,
    int M, int N, int K)
{
  __shared__ __align__(16) unsigned short As[128 * 40];  // stride 40 (+8 pad, 16B-aligned rows)
  __shared__ __align__(16) unsigned short Bs[128 * 40];

  const int tid  = threadIdx.x;
  const int lane = tid & 63;
  const int wave = tid >> 6;
  const int quad = lane >> 4;
  const int l16  = lane & 15;
  const int wr   = wave >> 1, wc = wave & 1;
  const long bm  = (long)blockIdx.y * 128;
  const long bn  = (long)blockIdx.x * 128;

  floatx4 acc[4][4];
#pragma unroll
  for (int i = 0; i < 4; ++i)
#pragma unroll
    for (int j = 0; j < 4; ++j) acc[i][j] = (floatx4){0.f, 0.f, 0.f, 0.f};

  const int srow = tid >> 2;  // 0..63 ; staging: rows srow, srow+64; chunk col cc
  const int cc   = tid & 3;

  for (int k0 = 0; k0 < K; k0 += 32) {
    __syncthreads();  // previous iteration's reads complete before overwrite
#pragma unroll
    for (int r = 0; r < 2; ++r) {
      const int row = srow + r * 64;
      short8 av, bv;
      if (A_BF16) {
        av = *(const short8*)((const unsigned short*)Aptr + (bm + row) * (long)K + k0 + cc * 8);
      } else {
        const float* ap = (const float*)Aptr + (bm + row) * (long)K + k0 + cc * 8;
        float4 f0 = *(const float4*)ap;
        float4 f1 = *(const float4*)(ap + 4);
        av = (short8){f2bf(f0.x), f2bf(f0.y), f2bf(f0.z), f2bf(f0.w),
                      f2bf(f1.x), f2bf(f1.y), f2bf(f1.z), f2bf(f1.w)};
      }
      {
        const float* bp = Bt + (bn + row) * (long)K + k0 + cc * 8;
        float4 g0 = *(const float4*)bp;
        float4 g1 = *(const float4*)(bp + 4);
        bv = (short8){f2bf(g0.x), f2bf(g0.y), f2bf(g0.z), f2bf(g0.w),
                      f2bf(g1.x), f2bf(g1.y), f2bf(g1.z), f2bf(g1.w)};
      }
      *(short8*)&As[row * 40 + cc * 8] = av;
      *(short8*)&Bs[row * 40 + cc * 8] = bv;
    }
    __syncthreads();

    short8 af[4], bf[4];
#pragma unroll
    for (int t = 0; t < 4; ++t) {
      af[t] = *(const short8*)&As[(wr * 64 + t * 16 + l16) * 40 + quad * 8];
      bf[t] = *(const short8*)&Bs[(wc * 64 + t * 16 + l16) * 40 + quad * 8];
    }
#pragma unroll
    for (int mt = 0; mt < 4; ++mt)
#pragma unroll
      for (int nt = 0; nt < 4; ++nt)
        acc[mt][nt] = __builtin_amdgcn_mfma_f32_16x16x32_bf16(af[mt], bf[nt], acc[mt][nt], 0, 0, 0);
  }

  // epilogue: D[row=quad*4+reg][col=l16]
#pragma unroll
  for (int nt = 0; nt < 4; ++nt) {
    const long col = bn + wc * 64 + nt * 16 + l16;
    const float bval = bias[col];
#pragma unroll
    for (int mt = 0; mt < 4; ++mt) {
#pragma unroll
      for (int rg = 0; rg < 4; ++rg) {
        const long row = bm + wr * 64 + mt * 16 + quad * 4 + rg;
        const float v = acc[mt][nt][rg] + bval;
        if (OUT_BF16) ((unsigned short*)Cptr)[row * (long)N + col] = (unsigned short)f2bf(v);
        else          ((float*)Cptr)[row * (long)N + col] = v;
      }
    }
  }
}

// Flash attention, causal. Q,K,V,O: bf16 [B*S][D] head-interleaved ([B,S,H,HD]).
// Block = 256 thr (4 waves) handles one 64-row q-tile of one (b,h).
// Wave w owns q rows [w*16, w*16+16).
__global__ __launch_bounds__(256, 2) void flash_attn_k(
    const unsigned short* __restrict__ Q,
    const unsigned short* __restrict__ Kp,
    const unsigned short* __restrict__ Vp,
    unsigned short* __restrict__ O)
{
  constexpr int S = 2048, D = 2048, HD = 128;
  const float scale = 0.08838834764831845f;  // 1/sqrt(128)

  __shared__ __align__(16) unsigned short Qs[64 * 136];   // [qrow][d], stride 136
  __shared__ __align__(16) unsigned short Ks[64 * 136];   // [krow][d]
  __shared__ __align__(16) unsigned short Vst[128 * 72];  // transposed: [d][krow], stride 72
  __shared__ __align__(16) unsigned short Ps[64 * 72];    // [qrow][krow]

  const int tid  = threadIdx.x;
  const int lane = tid & 63;
  const int w    = tid >> 6;
  const int quad = lane >> 4;
  const int l16  = lane & 15;

  const int qt = blockIdx.x;          // 0..31
  const int bh = blockIdx.y;          // 0..31
  const int b = bh >> 4, h = bh & 15;
  const int qbase = qt * 64;
  const long headoff = (long)b * S * D + (long)h * HD;

  // stage Q tile (64 x 128)
  {
    const int srow = tid >> 4;   // + i*16
    const int ccq  = tid & 15;
#pragma unroll
    for (int i = 0; i < 4; ++i) {
      const int row = srow + i * 16;
      uint4 v = *(const uint4*)(Q + headoff + (long)(qbase + row) * D + ccq * 8);
      *(uint4*)&Qs[row * 136 + ccq * 8] = v;
    }
  }

  floatx4 o_acc[8];
#pragma unroll
  for (int t = 0; t < 8; ++t) o_acc[t] = (floatx4){0.f, 0.f, 0.f, 0.f};
  float m_i[4], l_i[4];
#pragma unroll
  for (int rg = 0; rg < 4; ++rg) { m_i[rg] = -INFINITY; l_i[rg] = 0.f; }

  for (int kt = 0; kt <= qt; ++kt) {
    const int kbase = kt * 64;
    __syncthreads();  // prev iteration reads of Ks/Vst done
    // stage K tile + transposed V tile
    {
      const int srow = tid >> 4;
      const int ccq  = tid & 15;
#pragma unroll
      for (int i = 0; i < 4; ++i) {
        const int row = srow + i * 16;
        uint4 kv = *(const uint4*)(Kp + headoff + (long)(kbase + row) * D + ccq * 8);
        *(uint4*)&Ks[row * 136 + ccq * 8] = kv;
        short8 vv = *(const short8*)(Vp + headoff + (long)(kbase + row) * D + ccq * 8);
#pragma unroll
        for (int j = 0; j < 8; ++j) Vst[(ccq * 8 + j) * 72 + row] = (unsigned short)vv[j];
      }
    }
    __syncthreads();

    // scores: S[16x64] per wave = Q strip [16x128] . K^T
    floatx4 sc[4];
#pragma unroll
    for (int nt = 0; nt < 4; ++nt) sc[nt] = (floatx4){0.f, 0.f, 0.f, 0.f};
#pragma unroll
    for (int ks = 0; ks < 4; ++ks) {
      short8 aq = *(const short8*)&Qs[(w * 16 + l16) * 136 + ks * 32 + quad * 8];
#pragma unroll
      for (int nt = 0; nt < 4; ++nt) {
        short8 bk = *(const short8*)&Ks[(nt * 16 + l16) * 136 + ks * 32 + quad * 8];
        sc[nt] = __builtin_amdgcn_mfma_f32_16x16x32_bf16(aq, bk, sc[nt], 0, 0, 0);
      }
    }

    // scale + causal mask; row r = quad*4+rg (global q row qbase + w*16 + quad*4 + rg)
    float sv[4][4];
    float rmax[4];
#pragma unroll
    for (int rg = 0; rg < 4; ++rg) rmax[rg] = -INFINITY;
    const int qrow0 = qbase + w * 16 + quad * 4;
#pragma unroll
    for (int nt = 0; nt < 4; ++nt) {
      const int kg = kbase + nt * 16 + l16;
#pragma unroll
      for (int rg = 0; rg < 4; ++rg) {
        float v = sc[nt][rg] * scale;
        if (kg > qrow0 + rg) v = -INFINITY;
        sv[nt][rg] = v;
        rmax[rg] = fmaxf(rmax[rg], v);
      }
    }
    // row reduce across the 16 lanes of the quad
#pragma unroll
    for (int rg = 0; rg < 4; ++rg) {
#pragma unroll
      for (int off = 1; off < 16; off <<= 1)
        rmax[rg] = fmaxf(rmax[rg], __shfl_xor(rmax[rg], off));
    }
    float alpha[4], rsum[4];
#pragma unroll
    for (int rg = 0; rg < 4; ++rg) {
      const float mn = fmaxf(m_i[rg], rmax[rg]);
      alpha[rg] = exp2f((m_i[rg] - mn) * LOG2E);
      m_i[rg] = mn;
      rsum[rg] = 0.f;
    }
#pragma unroll
    for (int nt = 0; nt < 4; ++nt) {
#pragma unroll
      for (int rg = 0; rg < 4; ++rg) {
        const float p = exp2f((sv[nt][rg] - m_i[rg]) * LOG2E);
        rsum[rg] += p;
        Ps[(w * 16 + quad * 4 + rg) * 72 + nt * 16 + l16] = (unsigned short)f2bf(p);
      }
    }
#pragma unroll
    for (int rg = 0; rg < 4; ++rg) {
#pragma unroll
      for (int off = 1; off < 16; off <<= 1)
        rsum[rg] += __shfl_xor(rsum[rg], off);
      l_i[rg] = l_i[rg] * alpha[rg] + rsum[rg];
    }
#pragma unroll
    for (int t = 0; t < 8; ++t)
#pragma unroll
      for (int rg = 0; rg < 4; ++rg) o_acc[t][rg] *= alpha[rg];

    __syncthreads();  // Ps visible to all lanes of the wave (cross-lane LDS)

    // O strip [16x128] += P[16x64] . V[64x128] ; V in transposed LDS (B-layout contiguous)
#pragma unroll
    for (int ks = 0; ks < 2; ++ks) {
      short8 ap = *(const short8*)&Ps[(w * 16 + l16) * 72 + ks * 32 + quad * 8];
#pragma unroll
      for (int t = 0; t < 8; ++t) {
        short8 bv = *(const short8*)&Vst[(t * 16 + l16) * 72 + ks * 32 + quad * 8];
        o_acc[t] = __builtin_amdgcn_mfma_f32_16x16x32_bf16(ap, bv, o_acc[t], 0, 0, 0);
      }
    }
  }

  // epilogue: O /= l, write bf16
  float rl[4];
#pragma unroll
  for (int rg = 0; rg < 4; ++rg) rl[rg] = 1.0f / l_i[rg];
#pragma unroll
  for (int t = 0; t < 8; ++t) {
#pragma unroll
    for (int rg = 0; rg < 4; ++rg) {
      const long row = qbase + w * 16 + quad * 4 + rg;
      O[headoff + row * (long)D + t * 16 + l16] = (unsigned short)f2bf(o_acc[t][rg] * rl[rg]);
    }
  }
}

extern "C" void kernel_launch(void* const* d_in, const int* in_sizes, int n_in,
                              void* d_out, int out_size, void* d_ws, size_t ws_size,
                              hipStream_t stream) {
  const float* query = (const float*)d_in[0];
  const float* key_  = (const float*)d_in[1];
  const float* value = (const float*)d_in[2];
  const float* Wq = (const float*)d_in[3];
  const float* bq = (const float*)d_in[4];
  const float* Wk = (const float*)d_in[5];
  const float* bk = (const float*)d_in[6];
  const float* Wv = (const float*)d_in[7];
  const float* bv = (const float*)d_in[8];
  const float* Wo = (const float*)d_in[9];
  const float* bo = (const float*)d_in[10];
  float* out = (float*)d_out;

  constexpr int Bz = 2, S = 2048, D = 2048;
  constexpr int M = Bz * S;                 // 4096
  constexpr long NELEM = (long)M * D;       // 8,388,608

  // workspace: Qp, Kp, Vp, Oa  (bf16 each) = 64 MB total
  unsigned short* Qp = (unsigned short*)d_ws;
  unsigned short* Kp = Qp + NELEM;
  unsigned short* Vp = Kp + NELEM;
  unsigned short* Oa = Vp + NELEM;

  dim3 gridG(D / 128, M / 128);  // (16, 32)
  gemm_bias_k<false, true><<<gridG, 256, 0, stream>>>(query, Wq, bq, Qp, M, D, D);
  gemm_bias_k<false, true><<<gridG, 256, 0, stream>>>(key_,  Wk, bk, Kp, M, D, D);
  gemm_bias_k<false, true><<<gridG, 256, 0, stream>>>(value, Wv, bv, Vp, M, D, D);

  flash_attn_k<<<dim3(S / 64, 32), 256, 0, stream>>>(Qp, Kp, Vp, Oa);

  gemm_bias_k<true, false><<<gridG, 256, 0, stream>>>(Oa, Wo, bo, out, M, D, D);
}

// Round 2
// 863.240 us; speedup vs baseline: 1.2865x; 1.2865x over previous
//
#include <hip/hip_runtime.h>
#include <hip/hip_bf16.h>

// B=2, S=2048, D=2048, H=16, HD=128, causal MHA with 4 linear projections.
// Pipeline: QKV proj GEMMs (V writes transposed Vt[bh][d][s]) -> flash attn -> out proj.

#define LOG2E 1.44269504088896340736f

typedef __attribute__((ext_vector_type(8))) short short8;   // 8 x bf16
typedef __attribute__((ext_vector_type(4))) float floatx4;  // MFMA acc

__device__ __forceinline__ short f2bf(float f) {
  unsigned int u = __builtin_bit_cast(unsigned int, f);
  u += 0x7FFFu + ((u >> 16) & 1u);  // RNE
  return (short)(u >> 16);
}

// C = alpha * (A[M][K] * Bt[N][K]^T + bias[N])
// A fp32 or bf16; Bt fp32 weights (converted on the fly).
// VT_OUT: write output transposed per head: Vt[(b*16+h)*128 + dcol][s] (bf16).
// Block 256 thr, tile 128x128, BK=32; wave (wr,wc) does 64x64 via 4x4 16x16x32 MFMA.
template<bool A_BF16, bool OUT_BF16, bool VT_OUT>
__global__ __launch_bounds__(256, 2) void gemm_bias_k(
    const void* __restrict__ Aptr, const float* __restrict__ Bt,
    const float* __restrict__ bias, void* __restrict__ Cptr,
    int M, int N, int K, float alpha)
{
  // union: staging As/Bs (2 x 128x40 shorts = 20.5 KB) vs transpose buffer Ct (128x136 = 34.8 KB)
  __shared__ __align__(16) unsigned short smem[128 * 136];
  unsigned short* As = smem;               // [128][40]
  unsigned short* Bs = smem + 128 * 40;    // [128][40]

  const int tid  = threadIdx.x;
  const int lane = tid & 63;
  const int wave = tid >> 6;
  const int quad = lane >> 4;
  const int l16  = lane & 15;
  const int wr   = wave >> 1, wc = wave & 1;
  const long bm  = (long)blockIdx.y * 128;
  const long bn  = (long)blockIdx.x * 128;

  floatx4 acc[4][4];
#pragma unroll
  for (int i = 0; i < 4; ++i)
#pragma unroll
    for (int j = 0; j < 4; ++j) acc[i][j] = (floatx4){0.f, 0.f, 0.f, 0.f};

  const int srow = tid >> 2;
  const int cc   = tid & 3;

  for (int k0 = 0; k0 < K; k0 += 32) {
    __syncthreads();
#pragma unroll
    for (int r = 0; r < 2; ++r) {
      const int row = srow + r * 64;
      short8 av, bv;
      if (A_BF16) {
        av = *(const short8*)((const unsigned short*)Aptr + (bm + row) * (long)K + k0 + cc * 8);
      } else {
        const float* ap = (const float*)Aptr + (bm + row) * (long)K + k0 + cc * 8;
        float4 f0 = *(const float4*)ap;
        float4 f1 = *(const float4*)(ap + 4);
        av = (short8){f2bf(f0.x), f2bf(f0.y), f2bf(f0.z), f2bf(f0.w),
                      f2bf(f1.x), f2bf(f1.y), f2bf(f1.z), f2bf(f1.w)};
      }
      {
        const float* bp = Bt + (bn + row) * (long)K + k0 + cc * 8;
        float4 g0 = *(const float4*)bp;
        float4 g1 = *(const float4*)(bp + 4);
        bv = (short8){f2bf(g0.x), f2bf(g0.y), f2bf(g0.z), f2bf(g0.w),
                      f2bf(g1.x), f2bf(g1.y), f2bf(g1.z), f2bf(g1.w)};
      }
      *(short8*)&As[row * 40 + cc * 8] = av;
      *(short8*)&Bs[row * 40 + cc * 8] = bv;
    }
    __syncthreads();

    short8 af[4], bf[4];
#pragma unroll
    for (int t = 0; t < 4; ++t) {
      af[t] = *(const short8*)&As[(wr * 64 + t * 16 + l16) * 40 + quad * 8];
      bf[t] = *(const short8*)&Bs[(wc * 64 + t * 16 + l16) * 40 + quad * 8];
    }
#pragma unroll
    for (int mt = 0; mt < 4; ++mt)
#pragma unroll
      for (int nt = 0; nt < 4; ++nt)
        acc[mt][nt] = __builtin_amdgcn_mfma_f32_16x16x32_bf16(af[mt], bf[nt], acc[mt][nt], 0, 0, 0);
  }

  if (VT_OUT) {
    // transpose epilogue: Ct[col_local][row_local], then coalesced vector writes to Vt.
    __syncthreads();
    unsigned short* Ct = smem;  // [128][136]
#pragma unroll
    for (int nt = 0; nt < 4; ++nt) {
      const long col = bn + wc * 64 + nt * 16 + l16;
      const float bval = bias[col];
      const int col_l = wc * 64 + nt * 16 + l16;
#pragma unroll
      for (int mt = 0; mt < 4; ++mt) {
        const int row_l = wr * 64 + mt * 16 + quad * 4;
#pragma unroll
        for (int rg = 0; rg < 4; ++rg)
          Ct[col_l * 136 + row_l + rg] = (unsigned short)f2bf((acc[mt][nt][rg] + bval) * alpha);
      }
    }
    __syncthreads();
    // Vt[(b*16+h)*128 + dcol][s]; h == blockIdx.x (N=2048, 128-wide col-blocks)
    const int b  = (int)(bm >> 11);
    const int s0 = (int)(bm & 2047);
    const int r    = tid >> 1;      // dcol 0..127
    const int half = tid & 1;
    unsigned short* dst = (unsigned short*)Cptr +
        ((long)(b * 16 + blockIdx.x) * 128 + r) * 2048 + s0 + half * 64;
    const unsigned short* src = &Ct[r * 136 + half * 64];
#pragma unroll
    for (int c = 0; c < 8; ++c)
      *(uint4*)(dst + c * 8) = *(const uint4*)(src + c * 8);
  } else {
#pragma unroll
    for (int nt = 0; nt < 4; ++nt) {
      const long col = bn + wc * 64 + nt * 16 + l16;
      const float bval = bias[col];
#pragma unroll
      for (int mt = 0; mt < 4; ++mt) {
#pragma unroll
        for (int rg = 0; rg < 4; ++rg) {
          const long row = bm + wr * 64 + mt * 16 + quad * 4 + rg;
          const float v = (acc[mt][nt][rg] + bval) * alpha;
          if (OUT_BF16) ((unsigned short*)Cptr)[row * (long)N + col] = (unsigned short)f2bf(v);
          else          ((float*)Cptr)[row * (long)N + col] = v;
        }
      }
    }
  }
}

// Flash attention, causal. Q,K: bf16 [B,S,H,HD] row-major (Q pre-scaled by SCALE*LOG2E).
// Vt: bf16 [B*H][HD][S] (transposed per head). O: bf16 [B,S,H,HD].
// Block 256 thr = 4 waves; processes q-tile pair {pairIdx, 31-pairIdx} (64 rows each)
// sequentially -> uniform 33 k-tiles per block, 512 blocks all resident at 3/CU.
__global__ __launch_bounds__(256, 3) void flash_attn_k(
    const unsigned short* __restrict__ Q,
    const unsigned short* __restrict__ Kp,
    const unsigned short* __restrict__ Vt,
    unsigned short* __restrict__ O)
{
  constexpr int S = 2048, D = 2048, HD = 128;

  __shared__ __align__(16) unsigned short Ks[64 * 136];   // [krow][d]
  __shared__ __align__(16) unsigned short Vst[128 * 72];  // [d][krow]
  __shared__ __align__(16) unsigned short Ps[64 * 72];    // [qrow][krow]

  const int tid  = threadIdx.x;
  const int lane = tid & 63;
  const int w    = tid >> 6;
  const int quad = lane >> 4;
  const int l16  = lane & 15;

  const int bh = blockIdx.y;               // b*16 + h
  const long headoff = (long)(bh >> 4) * S * D + (long)(bh & 15) * HD;
  const long vtoff   = (long)bh * HD * S;

  const int sK_row = tid >> 4, sK_col = (tid & 15) * 8;   // K staging
  const int sV_row = tid >> 1, sV_col = (tid & 1) * 32;   // Vt staging

#pragma unroll 1
  for (int p = 0; p < 2; ++p) {
    const int qt = p ? (31 - (int)blockIdx.x) : (int)blockIdx.x;
    const int qbase = qt * 64;

    // Q fragments in registers (A-layout): row = qbase + w*16 + l16, k-chunks of 32
    short8 aq[4];
    {
      const unsigned short* qrow = Q + headoff + (long)(qbase + w * 16 + l16) * D;
#pragma unroll
      for (int ks = 0; ks < 4; ++ks)
        aq[ks] = *(const short8*)(qrow + ks * 32 + quad * 8);
    }

    floatx4 o_acc[8];
#pragma unroll
    for (int t = 0; t < 8; ++t) o_acc[t] = (floatx4){0.f, 0.f, 0.f, 0.f};
    float m_i[4], l_i[4];
#pragma unroll
    for (int rg = 0; rg < 4; ++rg) { m_i[rg] = -INFINITY; l_i[rg] = 0.f; }

    for (int kt = 0; kt <= qt; ++kt) {
      const int kbase = kt * 64;
      __syncthreads();  // protect Ks/Vst/Ps from previous iteration's readers
      // stage K tile [64][128] (vector, conflict-free streaming)
#pragma unroll
      for (int i = 0; i < 4; ++i) {
        const int row = sK_row + i * 16;
        *(uint4*)&Ks[row * 136 + sK_col] =
            *(const uint4*)(Kp + headoff + (long)(kbase + row) * D + sK_col);
      }
      // stage Vt tile [128 d][64 k] (vector — no transpose needed)
#pragma unroll
      for (int c = 0; c < 4; ++c) {
        *(uint4*)&Vst[sV_row * 72 + sV_col + c * 8] =
            *(const uint4*)(Vt + vtoff + (long)sV_row * S + kbase + sV_col + c * 8);
      }
      __syncthreads();

      // scores: per wave S[16 x 64] = Qstrip . K^T  (already in log2e*scale units)
      floatx4 sc[4];
#pragma unroll
      for (int nt = 0; nt < 4; ++nt) sc[nt] = (floatx4){0.f, 0.f, 0.f, 0.f};
#pragma unroll
      for (int ks = 0; ks < 4; ++ks) {
#pragma unroll
        for (int nt = 0; nt < 4; ++nt) {
          short8 bk = *(const short8*)&Ks[(nt * 16 + l16) * 136 + ks * 32 + quad * 8];
          sc[nt] = __builtin_amdgcn_mfma_f32_16x16x32_bf16(aq[ks], bk, sc[nt], 0, 0, 0);
        }
      }

      float sv[4][4];
      float rmax[4];
#pragma unroll
      for (int rg = 0; rg < 4; ++rg) rmax[rg] = -INFINITY;
      if (kt == qt) {  // diagonal tile: apply causal mask (block-uniform branch)
        const int qrow0 = qbase + w * 16 + quad * 4;
#pragma unroll
        for (int nt = 0; nt < 4; ++nt) {
          const int kg = kbase + nt * 16 + l16;
#pragma unroll
          for (int rg = 0; rg < 4; ++rg) {
            float v = sc[nt][rg];
            if (kg > qrow0 + rg) v = -INFINITY;
            sv[nt][rg] = v;
            rmax[rg] = fmaxf(rmax[rg], v);
          }
        }
      } else {
#pragma unroll
        for (int nt = 0; nt < 4; ++nt)
#pragma unroll
          for (int rg = 0; rg < 4; ++rg) {
            sv[nt][rg] = sc[nt][rg];
            rmax[rg] = fmaxf(rmax[rg], sc[nt][rg]);
          }
      }
#pragma unroll
      for (int rg = 0; rg < 4; ++rg) {
#pragma unroll
        for (int off = 1; off < 16; off <<= 1)
          rmax[rg] = fmaxf(rmax[rg], __shfl_xor(rmax[rg], off));
      }
      float alpha[4], rsum[4];
#pragma unroll
      for (int rg = 0; rg < 4; ++rg) {
        const float mn = fmaxf(m_i[rg], rmax[rg]);
        alpha[rg] = exp2f(m_i[rg] - mn);
        m_i[rg] = mn;
        rsum[rg] = 0.f;
      }
#pragma unroll
      for (int nt = 0; nt < 4; ++nt) {
#pragma unroll
        for (int rg = 0; rg < 4; ++rg) {
          const float pe = exp2f(sv[nt][rg] - m_i[rg]);
          rsum[rg] += pe;
          Ps[(w * 16 + quad * 4 + rg) * 72 + nt * 16 + l16] = (unsigned short)f2bf(pe);
        }
      }
#pragma unroll
      for (int rg = 0; rg < 4; ++rg) {
#pragma unroll
        for (int off = 1; off < 16; off <<= 1)
          rsum[rg] += __shfl_xor(rsum[rg], off);
        l_i[rg] = l_i[rg] * alpha[rg] + rsum[rg];
      }
#pragma unroll
      for (int t = 0; t < 8; ++t)
#pragma unroll
        for (int rg = 0; rg < 4; ++rg) o_acc[t][rg] *= alpha[rg];

      // no barrier: Ps region is wave-private (write->read within the same wave)
#pragma unroll
      for (int ks = 0; ks < 2; ++ks) {
        short8 ap = *(const short8*)&Ps[(w * 16 + l16) * 72 + ks * 32 + quad * 8];
#pragma unroll
        for (int t = 0; t < 8; ++t) {
          short8 bv = *(const short8*)&Vst[(t * 16 + l16) * 72 + ks * 32 + quad * 8];
          o_acc[t] = __builtin_amdgcn_mfma_f32_16x16x32_bf16(ap, bv, o_acc[t], 0, 0, 0);
        }
      }
    }

    float rl[4];
#pragma unroll
    for (int rg = 0; rg < 4; ++rg) rl[rg] = 1.0f / l_i[rg];
#pragma unroll
    for (int t = 0; t < 8; ++t) {
#pragma unroll
      for (int rg = 0; rg < 4; ++rg) {
        const long row = qbase + w * 16 + quad * 4 + rg;
        O[headoff + row * (long)D + t * 16 + l16] = (unsigned short)f2bf(o_acc[t][rg] * rl[rg]);
      }
    }
  }
}

extern "C" void kernel_launch(void* const* d_in, const int* in_sizes, int n_in,
                              void* d_out, int out_size, void* d_ws, size_t ws_size,
                              hipStream_t stream) {
  const float* query = (const float*)d_in[0];
  const float* key_  = (const float*)d_in[1];
  const float* value = (const float*)d_in[2];
  const float* Wq = (const float*)d_in[3];
  const float* bq = (const float*)d_in[4];
  const float* Wk = (const float*)d_in[5];
  const float* bk = (const float*)d_in[6];
  const float* Wv = (const float*)d_in[7];
  const float* bv = (const float*)d_in[8];
  const float* Wo = (const float*)d_in[9];
  const float* bo = (const float*)d_in[10];
  float* out = (float*)d_out;

  constexpr int Bz = 2, S = 2048, D = 2048;
  constexpr int M = Bz * S;
  constexpr long NELEM = (long)M * D;

  unsigned short* Qp = (unsigned short*)d_ws;
  unsigned short* Kp = Qp + NELEM;
  unsigned short* Vt = Kp + NELEM;   // [B*H][HD][S]
  unsigned short* Oa = Vt + NELEM;

  const float qscale = 0.08838834764831845f * LOG2E;  // 1/sqrt(128) * log2(e)

  dim3 gridG(D / 128, M / 128);
  gemm_bias_k<false, true, false><<<gridG, 256, 0, stream>>>(query, Wq, bq, Qp, M, D, D, qscale);
  gemm_bias_k<false, true, false><<<gridG, 256, 0, stream>>>(key_,  Wk, bk, Kp, M, D, D, 1.0f);
  gemm_bias_k<false, true, true ><<<gridG, 256, 0, stream>>>(value, Wv, bv, Vt, M, D, D, 1.0f);

  flash_attn_k<<<dim3(16, 32), 256, 0, stream>>>(Qp, Kp, Vt, Oa);

  gemm_bias_k<true, false, false><<<gridG, 256, 0, stream>>>(Oa, Wo, bo, out, M, D, D, 1.0f);
}

// Round 3
// 536.451 us; speedup vs baseline: 2.0701x; 1.6092x over previous
//
#include <hip/hip_runtime.h>
#include <hip/hip_bf16.h>

// B=2, S=2048, D=2048, H=16, HD=128, causal MHA with 4 linear projections.
// Full path: cvt fp32->bf16 (activations+weights) -> 3 bf16 GEMMs (V transposed)
//            -> flash attn -> out-proj GEMM (fp32 out). Fallback to fp32-staging
//            GEMMs if ws_size is too small.

#define LOG2E 1.44269504088896340736f

typedef __attribute__((ext_vector_type(8))) short short8;   // 8 x bf16
typedef __attribute__((ext_vector_type(4))) float floatx4;  // MFMA acc

__device__ __forceinline__ short f2bf(float f) {
  unsigned int u = __builtin_bit_cast(unsigned int, f);
  u += 0x7FFFu + ((u >> 16) & 1u);  // RNE
  return (short)(u >> 16);
}

__device__ __forceinline__ void gl_lds16(const void* g, void* l) {
  __builtin_amdgcn_global_load_lds(
      (const __attribute__((address_space(1))) unsigned int*)g,
      (__attribute__((address_space(3))) unsigned int*)l, 16, 0, 0);
}

// ---------------- fp32 -> bf16 conversion (up to 4 arrays per launch) -------
__global__ __launch_bounds__(256) void cvt_k(
    const float* __restrict__ s0, const float* __restrict__ s1,
    const float* __restrict__ s2, const float* __restrict__ s3,
    unsigned short* __restrict__ d0, unsigned short* __restrict__ d1,
    unsigned short* __restrict__ d2, unsigned short* __restrict__ d3, int n)
{
  const float* s; unsigned short* d;
  switch (blockIdx.y) {
    case 0: s = s0; d = d0; break;
    case 1: s = s1; d = d1; break;
    case 2: s = s2; d = d2; break;
    default: s = s3; d = d3; break;
  }
  const int i = (blockIdx.x * 256 + threadIdx.x) * 8;
  if (i >= n) return;
  float4 a = *(const float4*)(s + i);
  float4 b = *(const float4*)(s + i + 4);
  short8 v = (short8){f2bf(a.x), f2bf(a.y), f2bf(a.z), f2bf(a.w),
                      f2bf(b.x), f2bf(b.y), f2bf(b.z), f2bf(b.w)};
  *(short8*)(d + i) = v;
}

// ---------------- bf16 GEMM via global_load_lds + XOR-swizzled LDS ----------
// C = alpha * (A[M][K] * Bt[N][K]^T + bias[N]).  A,Bt bf16.
// Tile 128x128, BK=32, 4 waves; wave (wr,wc) does 64x64 via 4x4 16x16x32 MFMA.
// LDS tiles unpadded [128][32] bf16 with chunk swizzle cs = cg ^ ((row>>1)&3)
// (16B chunks) -> conflict-free staging AND ds_read_b128 fragment reads.
template<bool OUT_BF16, bool VT_OUT>
__global__ __launch_bounds__(256, 2) void gemm_bf16_k(
    const unsigned short* __restrict__ A, const unsigned short* __restrict__ Bt,
    const float* __restrict__ bias, void* __restrict__ Cptr,
    int M, int N, int K, float alpha)
{
  __shared__ __align__(16) unsigned short smem[VT_OUT ? 128 * 136 : 128 * 64];
  unsigned short* As = smem;             // [128][32] swizzled
  unsigned short* Bs = smem + 128 * 32;  // [128][32] swizzled

  const int tid  = threadIdx.x;
  const int lane = tid & 63;
  const int wave = tid >> 6;
  const int quad = lane >> 4;
  const int l16  = lane & 15;
  const int wr   = wave >> 1, wc = wave & 1;
  const long bm  = (long)blockIdx.y * 128;
  const long bn  = (long)blockIdx.x * 128;

  // staging plan: 8 chunks-instructions total for A (512 16B-chunks), 2 per wave
  const unsigned short* agp[2]; const unsigned short* bgp[2];
  unsigned short* alp[2]; unsigned short* blp[2];
#pragma unroll
  for (int j = 0; j < 2; ++j) {
    const int p = (wave * 2 + j) * 64 + lane;  // chunk position 0..511
    const int r = p >> 2, cs = p & 3;
    const int cg = cs ^ ((r >> 1) & 3);        // global chunk this LDS slot holds
    agp[j] = A  + (bm + r) * (long)K + cg * 8;
    bgp[j] = Bt + (bn + r) * (long)K + cg * 8;
    alp[j] = As + p * 8;
    blp[j] = Bs + p * 8;
  }

  floatx4 acc[4][4];
#pragma unroll
  for (int i = 0; i < 4; ++i)
#pragma unroll
    for (int j = 0; j < 4; ++j) acc[i][j] = (floatx4){0.f, 0.f, 0.f, 0.f};

  const int coff = (quad ^ ((l16 >> 1) & 3)) * 8;  // swizzled fragment chunk

  for (int k0 = 0; k0 < K; k0 += 32) {
    __syncthreads();
    gl_lds16(agp[0] + k0, alp[0]);
    gl_lds16(agp[1] + k0, alp[1]);
    gl_lds16(bgp[0] + k0, blp[0]);
    gl_lds16(bgp[1] + k0, blp[1]);
    __syncthreads();

    short8 af[4], bf[4];
#pragma unroll
    for (int t = 0; t < 4; ++t) {
      af[t] = *(const short8*)&As[(wr * 64 + t * 16 + l16) * 32 + coff];
      bf[t] = *(const short8*)&Bs[(wc * 64 + t * 16 + l16) * 32 + coff];
    }
#pragma unroll
    for (int mt = 0; mt < 4; ++mt)
#pragma unroll
      for (int nt = 0; nt < 4; ++nt)
        acc[mt][nt] = __builtin_amdgcn_mfma_f32_16x16x32_bf16(af[mt], bf[nt], acc[mt][nt], 0, 0, 0);
  }

  if (VT_OUT) {
    __syncthreads();
    unsigned short* Ct = smem;  // [128 col][136] transpose buffer
#pragma unroll
    for (int nt = 0; nt < 4; ++nt) {
      const long col = bn + wc * 64 + nt * 16 + l16;
      const float bval = bias[col];
      const int col_l = wc * 64 + nt * 16 + l16;
#pragma unroll
      for (int mt = 0; mt < 4; ++mt) {
        const int row_l = wr * 64 + mt * 16 + quad * 4;
#pragma unroll
        for (int rg = 0; rg < 4; ++rg)
          Ct[col_l * 136 + row_l + rg] = (unsigned short)f2bf((acc[mt][nt][rg] + bval) * alpha);
      }
    }
    __syncthreads();
    // Vt[(b*16+h)*128 + dcol][s]; h == blockIdx.x (N=2048 -> 16 head-col-blocks)
    const int b  = (int)(bm >> 11);
    const int s0 = (int)(bm & 2047);
    const int r    = tid >> 1;
    const int half = tid & 1;
    unsigned short* dst = (unsigned short*)Cptr +
        ((long)(b * 16 + blockIdx.x) * 128 + r) * 2048 + s0 + half * 64;
    const unsigned short* src = &Ct[r * 136 + half * 64];
#pragma unroll
    for (int c = 0; c < 8; ++c)
      *(uint4*)(dst + c * 8) = *(const uint4*)(src + c * 8);
  } else {
#pragma unroll
    for (int nt = 0; nt < 4; ++nt) {
      const long col = bn + wc * 64 + nt * 16 + l16;
      const float bval = bias[col];
#pragma unroll
      for (int mt = 0; mt < 4; ++mt) {
#pragma unroll
        for (int rg = 0; rg < 4; ++rg) {
          const long row = bm + wr * 64 + mt * 16 + quad * 4 + rg;
          const float v = (acc[mt][nt][rg] + bval) * alpha;
          if (OUT_BF16) ((unsigned short*)Cptr)[row * (long)N + col] = (unsigned short)f2bf(v);
          else          ((float*)Cptr)[row * (long)N + col] = v;
        }
      }
    }
  }
}

// ---------------- fallback GEMM (fp32 operands, VALU conversion) ------------
template<bool A_BF16, bool OUT_BF16, bool VT_OUT>
__global__ __launch_bounds__(256, 2) void gemm_bias_k(
    const void* __restrict__ Aptr, const float* __restrict__ Bt,
    const float* __restrict__ bias, void* __restrict__ Cptr,
    int M, int N, int K, float alpha)
{
  __shared__ __align__(16) unsigned short smem[128 * 136];
  unsigned short* As = smem;
  unsigned short* Bs = smem + 128 * 40;

  const int tid  = threadIdx.x;
  const int lane = tid & 63;
  const int wave = tid >> 6;
  const int quad = lane >> 4;
  const int l16  = lane & 15;
  const int wr   = wave >> 1, wc = wave & 1;
  const long bm  = (long)blockIdx.y * 128;
  const long bn  = (long)blockIdx.x * 128;

  floatx4 acc[4][4];
#pragma unroll
  for (int i = 0; i < 4; ++i)
#pragma unroll
    for (int j = 0; j < 4; ++j) acc[i][j] = (floatx4){0.f, 0.f, 0.f, 0.f};

  const int srow = tid >> 2;
  const int cc   = tid & 3;

  for (int k0 = 0; k0 < K; k0 += 32) {
    __syncthreads();
#pragma unroll
    for (int r = 0; r < 2; ++r) {
      const int row = srow + r * 64;
      short8 av, bv;
      if (A_BF16) {
        av = *(const short8*)((const unsigned short*)Aptr + (bm + row) * (long)K + k0 + cc * 8);
      } else {
        const float* ap = (const float*)Aptr + (bm + row) * (long)K + k0 + cc * 8;
        float4 f0 = *(const float4*)ap;
        float4 f1 = *(const float4*)(ap + 4);
        av = (short8){f2bf(f0.x), f2bf(f0.y), f2bf(f0.z), f2bf(f0.w),
                      f2bf(f1.x), f2bf(f1.y), f2bf(f1.z), f2bf(f1.w)};
      }
      {
        const float* bp = Bt + (bn + row) * (long)K + k0 + cc * 8;
        float4 g0 = *(const float4*)bp;
        float4 g1 = *(const float4*)(bp + 4);
        bv = (short8){f2bf(g0.x), f2bf(g0.y), f2bf(g0.z), f2bf(g0.w),
                      f2bf(g1.x), f2bf(g1.y), f2bf(g1.z), f2bf(g1.w)};
      }
      *(short8*)&As[row * 40 + cc * 8] = av;
      *(short8*)&Bs[row * 40 + cc * 8] = bv;
    }
    __syncthreads();

    short8 af[4], bf[4];
#pragma unroll
    for (int t = 0; t < 4; ++t) {
      af[t] = *(const short8*)&As[(wr * 64 + t * 16 + l16) * 40 + quad * 8];
      bf[t] = *(const short8*)&Bs[(wc * 64 + t * 16 + l16) * 40 + quad * 8];
    }
#pragma unroll
    for (int mt = 0; mt < 4; ++mt)
#pragma unroll
      for (int nt = 0; nt < 4; ++nt)
        acc[mt][nt] = __builtin_amdgcn_mfma_f32_16x16x32_bf16(af[mt], bf[nt], acc[mt][nt], 0, 0, 0);
  }

  if (VT_OUT) {
    __syncthreads();
    unsigned short* Ct = smem;
#pragma unroll
    for (int nt = 0; nt < 4; ++nt) {
      const long col = bn + wc * 64 + nt * 16 + l16;
      const float bval = bias[col];
      const int col_l = wc * 64 + nt * 16 + l16;
#pragma unroll
      for (int mt = 0; mt < 4; ++mt) {
        const int row_l = wr * 64 + mt * 16 + quad * 4;
#pragma unroll
        for (int rg = 0; rg < 4; ++rg)
          Ct[col_l * 136 + row_l + rg] = (unsigned short)f2bf((acc[mt][nt][rg] + bval) * alpha);
      }
    }
    __syncthreads();
    const int b  = (int)(bm >> 11);
    const int s0 = (int)(bm & 2047);
    const int r    = tid >> 1;
    const int half = tid & 1;
    unsigned short* dst = (unsigned short*)Cptr +
        ((long)(b * 16 + blockIdx.x) * 128 + r) * 2048 + s0 + half * 64;
    const unsigned short* src = &Ct[r * 136 + half * 64];
#pragma unroll
    for (int c = 0; c < 8; ++c)
      *(uint4*)(dst + c * 8) = *(const uint4*)(src + c * 8);
  } else {
#pragma unroll
    for (int nt = 0; nt < 4; ++nt) {
      const long col = bn + wc * 64 + nt * 16 + l16;
      const float bval = bias[col];
#pragma unroll
      for (int mt = 0; mt < 4; ++mt) {
#pragma unroll
        for (int rg = 0; rg < 4; ++rg) {
          const long row = bm + wr * 64 + mt * 16 + quad * 4 + rg;
          const float v = (acc[mt][nt][rg] + bval) * alpha;
          if (OUT_BF16) ((unsigned short*)Cptr)[row * (long)N + col] = (unsigned short)f2bf(v);
          else          ((float*)Cptr)[row * (long)N + col] = v;
        }
      }
    }
  }
}

// ---------------- flash attention (unchanged from R2) -----------------------
__global__ __launch_bounds__(256, 3) void flash_attn_k(
    const unsigned short* __restrict__ Q,
    const unsigned short* __restrict__ Kp,
    const unsigned short* __restrict__ Vt,
    unsigned short* __restrict__ O)
{
  constexpr int S = 2048, D = 2048, HD = 128;

  __shared__ __align__(16) unsigned short Ks[64 * 136];
  __shared__ __align__(16) unsigned short Vst[128 * 72];
  __shared__ __align__(16) unsigned short Ps[64 * 72];

  const int tid  = threadIdx.x;
  const int lane = tid & 63;
  const int w    = tid >> 6;
  const int quad = lane >> 4;
  const int l16  = lane & 15;

  const int bh = blockIdx.y;
  const long headoff = (long)(bh >> 4) * S * D + (long)(bh & 15) * HD;
  const long vtoff   = (long)bh * HD * S;

  const int sK_row = tid >> 4, sK_col = (tid & 15) * 8;
  const int sV_row = tid >> 1, sV_col = (tid & 1) * 32;

#pragma unroll 1
  for (int p = 0; p < 2; ++p) {
    const int qt = p ? (31 - (int)blockIdx.x) : (int)blockIdx.x;
    const int qbase = qt * 64;

    short8 aq[4];
    {
      const unsigned short* qrow = Q + headoff + (long)(qbase + w * 16 + l16) * D;
#pragma unroll
      for (int ks = 0; ks < 4; ++ks)
        aq[ks] = *(const short8*)(qrow + ks * 32 + quad * 8);
    }

    floatx4 o_acc[8];
#pragma unroll
    for (int t = 0; t < 8; ++t) o_acc[t] = (floatx4){0.f, 0.f, 0.f, 0.f};
    float m_i[4], l_i[4];
#pragma unroll
    for (int rg = 0; rg < 4; ++rg) { m_i[rg] = -INFINITY; l_i[rg] = 0.f; }

    for (int kt = 0; kt <= qt; ++kt) {
      const int kbase = kt * 64;
      __syncthreads();
#pragma unroll
      for (int i = 0; i < 4; ++i) {
        const int row = sK_row + i * 16;
        *(uint4*)&Ks[row * 136 + sK_col] =
            *(const uint4*)(Kp + headoff + (long)(kbase + row) * D + sK_col);
      }
#pragma unroll
      for (int c = 0; c < 4; ++c) {
        *(uint4*)&Vst[sV_row * 72 + sV_col + c * 8] =
            *(const uint4*)(Vt + vtoff + (long)sV_row * S + kbase + sV_col + c * 8);
      }
      __syncthreads();

      floatx4 sc[4];
#pragma unroll
      for (int nt = 0; nt < 4; ++nt) sc[nt] = (floatx4){0.f, 0.f, 0.f, 0.f};
#pragma unroll
      for (int ks = 0; ks < 4; ++ks) {
#pragma unroll
        for (int nt = 0; nt < 4; ++nt) {
          short8 bk = *(const short8*)&Ks[(nt * 16 + l16) * 136 + ks * 32 + quad * 8];
          sc[nt] = __builtin_amdgcn_mfma_f32_16x16x32_bf16(aq[ks], bk, sc[nt], 0, 0, 0);
        }
      }

      float sv[4][4];
      float rmax[4];
#pragma unroll
      for (int rg = 0; rg < 4; ++rg) rmax[rg] = -INFINITY;
      if (kt == qt) {
        const int qrow0 = qbase + w * 16 + quad * 4;
#pragma unroll
        for (int nt = 0; nt < 4; ++nt) {
          const int kg = kbase + nt * 16 + l16;
#pragma unroll
          for (int rg = 0; rg < 4; ++rg) {
            float v = sc[nt][rg];
            if (kg > qrow0 + rg) v = -INFINITY;
            sv[nt][rg] = v;
            rmax[rg] = fmaxf(rmax[rg], v);
          }
        }
      } else {
#pragma unroll
        for (int nt = 0; nt < 4; ++nt)
#pragma unroll
          for (int rg = 0; rg < 4; ++rg) {
            sv[nt][rg] = sc[nt][rg];
            rmax[rg] = fmaxf(rmax[rg], sc[nt][rg]);
          }
      }
#pragma unroll
      for (int rg = 0; rg < 4; ++rg) {
#pragma unroll
        for (int off = 1; off < 16; off <<= 1)
          rmax[rg] = fmaxf(rmax[rg], __shfl_xor(rmax[rg], off));
      }
      float alpha[4], rsum[4];
#pragma unroll
      for (int rg = 0; rg < 4; ++rg) {
        const float mn = fmaxf(m_i[rg], rmax[rg]);
        alpha[rg] = exp2f(m_i[rg] - mn);
        m_i[rg] = mn;
        rsum[rg] = 0.f;
      }
#pragma unroll
      for (int nt = 0; nt < 4; ++nt) {
#pragma unroll
        for (int rg = 0; rg < 4; ++rg) {
          const float pe = exp2f(sv[nt][rg] - m_i[rg]);
          rsum[rg] += pe;
          Ps[(w * 16 + quad * 4 + rg) * 72 + nt * 16 + l16] = (unsigned short)f2bf(pe);
        }
      }
#pragma unroll
      for (int rg = 0; rg < 4; ++rg) {
#pragma unroll
        for (int off = 1; off < 16; off <<= 1)
          rsum[rg] += __shfl_xor(rsum[rg], off);
        l_i[rg] = l_i[rg] * alpha[rg] + rsum[rg];
      }
#pragma unroll
      for (int t = 0; t < 8; ++t)
#pragma unroll
        for (int rg = 0; rg < 4; ++rg) o_acc[t][rg] *= alpha[rg];

#pragma unroll
      for (int ks = 0; ks < 2; ++ks) {
        short8 ap = *(const short8*)&Ps[(w * 16 + l16) * 72 + ks * 32 + quad * 8];
#pragma unroll
        for (int t = 0; t < 8; ++t) {
          short8 bv = *(const short8*)&Vst[(t * 16 + l16) * 72 + ks * 32 + quad * 8];
          o_acc[t] = __builtin_amdgcn_mfma_f32_16x16x32_bf16(ap, bv, o_acc[t], 0, 0, 0);
        }
      }
    }

    float rl[4];
#pragma unroll
    for (int rg = 0; rg < 4; ++rg) rl[rg] = 1.0f / l_i[rg];
#pragma unroll
    for (int t = 0; t < 8; ++t) {
#pragma unroll
      for (int rg = 0; rg < 4; ++rg) {
        const long row = qbase + w * 16 + quad * 4 + rg;
        O[headoff + row * (long)D + t * 16 + l16] = (unsigned short)f2bf(o_acc[t][rg] * rl[rg]);
      }
    }
  }
}

extern "C" void kernel_launch(void* const* d_in, const int* in_sizes, int n_in,
                              void* d_out, int out_size, void* d_ws, size_t ws_size,
                              hipStream_t stream) {
  const float* query = (const float*)d_in[0];
  const float* key_  = (const float*)d_in[1];
  const float* value = (const float*)d_in[2];
  const float* Wq = (const float*)d_in[3];
  const float* bq = (const float*)d_in[4];
  const float* Wk = (const float*)d_in[5];
  const float* bk = (const float*)d_in[6];
  const float* Wv = (const float*)d_in[7];
  const float* bv = (const float*)d_in[8];
  const float* Wo = (const float*)d_in[9];
  const float* bo = (const float*)d_in[10];
  float* out = (float*)d_out;

  constexpr int Bz = 2, S = 2048, D = 2048;
  constexpr int M = Bz * S;                    // 4096
  constexpr long NELEM = (long)M * D;          // 8,388,608
  constexpr long WELEM = (long)D * D;          // 4,194,304

  const float qscale = 0.08838834764831845f * LOG2E;  // 1/sqrt(128) * log2(e)
  dim3 gridG(D / 128, M / 128);                       // (16, 32)

  const size_t need_full = (size_t)(6 * NELEM + 4 * WELEM) * 2;  // 134.2 MB

  if (ws_size >= need_full) {
    unsigned short* Qp  = (unsigned short*)d_ws;
    unsigned short* Kp  = Qp + NELEM;
    unsigned short* Vt  = Kp + NELEM;
    unsigned short* Xq  = Vt + NELEM;   // dead after Q-GEMM; reused as Oa
    unsigned short* Xk  = Xq + NELEM;
    unsigned short* Xv  = Xk + NELEM;
    unsigned short* Wqb = Xv + NELEM;
    unsigned short* Wkb = Wqb + WELEM;
    unsigned short* Wvb = Wkb + WELEM;
    unsigned short* Wob = Wvb + WELEM;
    unsigned short* Oa  = Xq;

    // fp32 -> bf16: 3 activations (NELEM each), 4 weights (WELEM each)
    cvt_k<<<dim3(NELEM / (8 * 256), 3), 256, 0, stream>>>(
        query, key_, value, value, Xq, Xk, Xv, Xv, (int)NELEM);
    cvt_k<<<dim3(WELEM / (8 * 256), 4), 256, 0, stream>>>(
        Wq, Wk, Wv, Wo, Wqb, Wkb, Wvb, Wob, (int)WELEM);

    gemm_bf16_k<true, false><<<gridG, 256, 0, stream>>>(Xq, Wqb, bq, Qp, M, D, D, qscale);
    gemm_bf16_k<true, false><<<gridG, 256, 0, stream>>>(Xk, Wkb, bk, Kp, M, D, D, 1.0f);
    gemm_bf16_k<true, true ><<<gridG, 256, 0, stream>>>(Xv, Wvb, bv, Vt, M, D, D, 1.0f);

    flash_attn_k<<<dim3(16, 32), 256, 0, stream>>>(Qp, Kp, Vt, Oa);

    gemm_bf16_k<false, false><<<gridG, 256, 0, stream>>>(Oa, Wob, bo, out, M, D, D, 1.0f);
  } else {
    unsigned short* Qp = (unsigned short*)d_ws;
    unsigned short* Kp = Qp + NELEM;
    unsigned short* Vt = Kp + NELEM;
    unsigned short* Oa = Vt + NELEM;

    gemm_bias_k<false, true, false><<<gridG, 256, 0, stream>>>(query, Wq, bq, Qp, M, D, D, qscale);
    gemm_bias_k<false, true, false><<<gridG, 256, 0, stream>>>(key_,  Wk, bk, Kp, M, D, D, 1.0f);
    gemm_bias_k<false, true, true ><<<gridG, 256, 0, stream>>>(value, Wv, bv, Vt, M, D, D, 1.0f);

    flash_attn_k<<<dim3(16, 32), 256, 0, stream>>>(Qp, Kp, Vt, Oa);

    gemm_bias_k<true, false, false><<<gridG, 256, 0, stream>>>(Oa, Wo, bo, out, M, D, D, 1.0f);
  }
}

// Round 4
// 524.113 us; speedup vs baseline: 2.1189x; 1.0235x over previous
//
#include <hip/hip_runtime.h>
#include <hip/hip_bf16.h>

// B=2, S=2048, D=2048, H=16, HD=128, causal MHA with 4 linear projections.
// cvt fp32->bf16 -> 3 bf16 GEMMs (V transposed per head) -> flash attn (transposed
// score layout, per-lane softmax rows) -> out-proj GEMM (fp32 out).

#define LOG2E 1.44269504088896340736f

typedef __attribute__((ext_vector_type(8))) short short8;    // 8 x bf16
typedef __attribute__((ext_vector_type(4))) short short4b;   // 4 x bf16
typedef __attribute__((ext_vector_type(4))) float floatx4;   // MFMA acc

__device__ __forceinline__ short f2bf(float f) {
  unsigned int u = __builtin_bit_cast(unsigned int, f);
  u += 0x7FFFu + ((u >> 16) & 1u);  // RNE
  return (short)(u >> 16);
}

__device__ __forceinline__ void gl_lds16(const void* g, void* l) {
  __builtin_amdgcn_global_load_lds(
      (const __attribute__((address_space(1))) unsigned int*)g,
      (__attribute__((address_space(3))) unsigned int*)l, 16, 0, 0);
}

// ---------------- fp32 -> bf16 conversion (up to 4 arrays per launch) -------
__global__ __launch_bounds__(256) void cvt_k(
    const float* __restrict__ s0, const float* __restrict__ s1,
    const float* __restrict__ s2, const float* __restrict__ s3,
    unsigned short* __restrict__ d0, unsigned short* __restrict__ d1,
    unsigned short* __restrict__ d2, unsigned short* __restrict__ d3, int n)
{
  const float* s; unsigned short* d;
  switch (blockIdx.y) {
    case 0: s = s0; d = d0; break;
    case 1: s = s1; d = d1; break;
    case 2: s = s2; d = d2; break;
    default: s = s3; d = d3; break;
  }
  const int i = (blockIdx.x * 256 + threadIdx.x) * 8;
  if (i >= n) return;
  float4 a = *(const float4*)(s + i);
  float4 b = *(const float4*)(s + i + 4);
  short8 v = (short8){f2bf(a.x), f2bf(a.y), f2bf(a.z), f2bf(a.w),
                      f2bf(b.x), f2bf(b.y), f2bf(b.z), f2bf(b.w)};
  *(short8*)(d + i) = v;
}

// ---------------- bf16 GEMM via global_load_lds + XOR-swizzled LDS ----------
template<bool OUT_BF16, bool VT_OUT>
__global__ __launch_bounds__(256, 2) void gemm_bf16_k(
    const unsigned short* __restrict__ A, const unsigned short* __restrict__ Bt,
    const float* __restrict__ bias, void* __restrict__ Cptr,
    int M, int N, int K, float alpha)
{
  __shared__ __align__(16) unsigned short smem[VT_OUT ? 128 * 136 : 128 * 64];
  unsigned short* As = smem;             // [128][32] swizzled
  unsigned short* Bs = smem + 128 * 32;  // [128][32] swizzled

  const int tid  = threadIdx.x;
  const int lane = tid & 63;
  const int wave = tid >> 6;
  const int quad = lane >> 4;
  const int l16  = lane & 15;
  const int wr   = wave >> 1, wc = wave & 1;
  const long bm  = (long)blockIdx.y * 128;
  const long bn  = (long)blockIdx.x * 128;

  const unsigned short* agp[2]; const unsigned short* bgp[2];
  unsigned short* alp[2]; unsigned short* blp[2];
#pragma unroll
  for (int j = 0; j < 2; ++j) {
    const int p = (wave * 2 + j) * 64 + lane;  // chunk slot 0..511
    const int r = p >> 2, cs = p & 3;
    const int cg = cs ^ ((r >> 1) & 3);
    agp[j] = A  + (bm + r) * (long)K + cg * 8;
    bgp[j] = Bt + (bn + r) * (long)K + cg * 8;
    alp[j] = As + p * 8;
    blp[j] = Bs + p * 8;
  }

  floatx4 acc[4][4];
#pragma unroll
  for (int i = 0; i < 4; ++i)
#pragma unroll
    for (int j = 0; j < 4; ++j) acc[i][j] = (floatx4){0.f, 0.f, 0.f, 0.f};

  const int coff = (quad ^ ((l16 >> 1) & 3)) * 8;

  for (int k0 = 0; k0 < K; k0 += 32) {
    __syncthreads();
    gl_lds16(agp[0] + k0, alp[0]);
    gl_lds16(agp[1] + k0, alp[1]);
    gl_lds16(bgp[0] + k0, blp[0]);
    gl_lds16(bgp[1] + k0, blp[1]);
    __syncthreads();

    short8 af[4], bf[4];
#pragma unroll
    for (int t = 0; t < 4; ++t) {
      af[t] = *(const short8*)&As[(wr * 64 + t * 16 + l16) * 32 + coff];
      bf[t] = *(const short8*)&Bs[(wc * 64 + t * 16 + l16) * 32 + coff];
    }
#pragma unroll
    for (int mt = 0; mt < 4; ++mt)
#pragma unroll
      for (int nt = 0; nt < 4; ++nt)
        acc[mt][nt] = __builtin_amdgcn_mfma_f32_16x16x32_bf16(af[mt], bf[nt], acc[mt][nt], 0, 0, 0);
  }

  if (VT_OUT) {
    __syncthreads();
    unsigned short* Ct = smem;  // [128 col][136]
#pragma unroll
    for (int nt = 0; nt < 4; ++nt) {
      const long col = bn + wc * 64 + nt * 16 + l16;
      const float bval = bias[col];
      const int col_l = wc * 64 + nt * 16 + l16;
#pragma unroll
      for (int mt = 0; mt < 4; ++mt) {
        const int row_l = wr * 64 + mt * 16 + quad * 4;
#pragma unroll
        for (int rg = 0; rg < 4; ++rg)
          Ct[col_l * 136 + row_l + rg] = (unsigned short)f2bf((acc[mt][nt][rg] + bval) * alpha);
      }
    }
    __syncthreads();
    const int b  = (int)(bm >> 11);
    const int s0 = (int)(bm & 2047);
    const int r    = tid >> 1;
    const int half = tid & 1;
    unsigned short* dst = (unsigned short*)Cptr +
        ((long)(b * 16 + blockIdx.x) * 128 + r) * 2048 + s0 + half * 64;
    const unsigned short* src = &Ct[r * 136 + half * 64];
#pragma unroll
    for (int c = 0; c < 8; ++c)
      *(uint4*)(dst + c * 8) = *(const uint4*)(src + c * 8);
  } else {
#pragma unroll
    for (int nt = 0; nt < 4; ++nt) {
      const long col = bn + wc * 64 + nt * 16 + l16;
      const float bval = bias[col];
#pragma unroll
      for (int mt = 0; mt < 4; ++mt) {
#pragma unroll
        for (int rg = 0; rg < 4; ++rg) {
          const long row = bm + wr * 64 + mt * 16 + quad * 4 + rg;
          const float v = (acc[mt][nt][rg] + bval) * alpha;
          if (OUT_BF16) ((unsigned short*)Cptr)[row * (long)N + col] = (unsigned short)f2bf(v);
          else          ((float*)Cptr)[row * (long)N + col] = v;
        }
      }
    }
  }
}

// ---------------- fallback GEMM (fp32 operands) -----------------------------
template<bool A_BF16, bool OUT_BF16, bool VT_OUT>
__global__ __launch_bounds__(256, 2) void gemm_bias_k(
    const void* __restrict__ Aptr, const float* __restrict__ Bt,
    const float* __restrict__ bias, void* __restrict__ Cptr,
    int M, int N, int K, float alpha)
{
  __shared__ __align__(16) unsigned short smem[128 * 136];
  unsigned short* As = smem;
  unsigned short* Bs = smem + 128 * 40;

  const int tid  = threadIdx.x;
  const int lane = tid & 63;
  const int wave = tid >> 6;
  const int quad = lane >> 4;
  const int l16  = lane & 15;
  const int wr   = wave >> 1, wc = wave & 1;
  const long bm  = (long)blockIdx.y * 128;
  const long bn  = (long)blockIdx.x * 128;

  floatx4 acc[4][4];
#pragma unroll
  for (int i = 0; i < 4; ++i)
#pragma unroll
    for (int j = 0; j < 4; ++j) acc[i][j] = (floatx4){0.f, 0.f, 0.f, 0.f};

  const int srow = tid >> 2;
  const int cc   = tid & 3;

  for (int k0 = 0; k0 < K; k0 += 32) {
    __syncthreads();
#pragma unroll
    for (int r = 0; r < 2; ++r) {
      const int row = srow + r * 64;
      short8 av, bv;
      if (A_BF16) {
        av = *(const short8*)((const unsigned short*)Aptr + (bm + row) * (long)K + k0 + cc * 8);
      } else {
        const float* ap = (const float*)Aptr + (bm + row) * (long)K + k0 + cc * 8;
        float4 f0 = *(const float4*)ap;
        float4 f1 = *(const float4*)(ap + 4);
        av = (short8){f2bf(f0.x), f2bf(f0.y), f2bf(f0.z), f2bf(f0.w),
                      f2bf(f1.x), f2bf(f1.y), f2bf(f1.z), f2bf(f1.w)};
      }
      {
        const float* bp = Bt + (bn + row) * (long)K + k0 + cc * 8;
        float4 g0 = *(const float4*)bp;
        float4 g1 = *(const float4*)(bp + 4);
        bv = (short8){f2bf(g0.x), f2bf(g0.y), f2bf(g0.z), f2bf(g0.w),
                      f2bf(g1.x), f2bf(g1.y), f2bf(g1.z), f2bf(g1.w)};
      }
      *(short8*)&As[row * 40 + cc * 8] = av;
      *(short8*)&Bs[row * 40 + cc * 8] = bv;
    }
    __syncthreads();

    short8 af[4], bf[4];
#pragma unroll
    for (int t = 0; t < 4; ++t) {
      af[t] = *(const short8*)&As[(wr * 64 + t * 16 + l16) * 40 + quad * 8];
      bf[t] = *(const short8*)&Bs[(wc * 64 + t * 16 + l16) * 40 + quad * 8];
    }
#pragma unroll
    for (int mt = 0; mt < 4; ++mt)
#pragma unroll
      for (int nt = 0; nt < 4; ++nt)
        acc[mt][nt] = __builtin_amdgcn_mfma_f32_16x16x32_bf16(af[mt], bf[nt], acc[mt][nt], 0, 0, 0);
  }

  if (VT_OUT) {
    __syncthreads();
    unsigned short* Ct = smem;
#pragma unroll
    for (int nt = 0; nt < 4; ++nt) {
      const long col = bn + wc * 64 + nt * 16 + l16;
      const float bval = bias[col];
      const int col_l = wc * 64 + nt * 16 + l16;
#pragma unroll
      for (int mt = 0; mt < 4; ++mt) {
        const int row_l = wr * 64 + mt * 16 + quad * 4;
#pragma unroll
        for (int rg = 0; rg < 4; ++rg)
          Ct[col_l * 136 + row_l + rg] = (unsigned short)f2bf((acc[mt][nt][rg] + bval) * alpha);
      }
    }
    __syncthreads();
    const int b  = (int)(bm >> 11);
    const int s0 = (int)(bm & 2047);
    const int r    = tid >> 1;
    const int half = tid & 1;
    unsigned short* dst = (unsigned short*)Cptr +
        ((long)(b * 16 + blockIdx.x) * 128 + r) * 2048 + s0 + half * 64;
    const unsigned short* src = &Ct[r * 136 + half * 64];
#pragma unroll
    for (int c = 0; c < 8; ++c)
      *(uint4*)(dst + c * 8) = *(const uint4*)(src + c * 8);
  } else {
#pragma unroll
    for (int nt = 0; nt < 4; ++nt) {
      const long col = bn + wc * 64 + nt * 16 + l16;
      const float bval = bias[col];
#pragma unroll
      for (int mt = 0; mt < 4; ++mt) {
#pragma unroll
        for (int rg = 0; rg < 4; ++rg) {
          const long row = bm + wr * 64 + mt * 16 + quad * 4 + rg;
          const float v = (acc[mt][nt][rg] + bval) * alpha;
          if (OUT_BF16) ((unsigned short*)Cptr)[row * (long)N + col] = (unsigned short)f2bf(v);
          else          ((float*)Cptr)[row * (long)N + col] = v;
        }
      }
    }
  }
}

// ---------------- flash attention, transposed-score layout ------------------
// Q,K,O: bf16 [B,S,H,HD] (Q pre-scaled by SCALE*LOG2E). Vt: bf16 [B*H][HD][S].
// Block 256 thr = 4 waves, q-tile 128 rows; wave owns 32 q-rows (2 strips of 16).
// Scores computed as S^T = K.Q^T so each lane owns one q-row (col=l16):
// softmax reductions = in-lane + 2 shuffles. O computed as O^T = Vt.P^T.
// K/V staged via global_load_lds into XOR-swizzled unpadded LDS.
__global__ __launch_bounds__(256, 3) void flash_attn_k(
    const unsigned short* __restrict__ Q,
    const unsigned short* __restrict__ Kp,
    const unsigned short* __restrict__ Vt,
    unsigned short* __restrict__ O)
{
  constexpr int S = 2048, D = 2048, HD = 128;
  constexpr int PS = 72;  // Ps stride (shorts), 144 B (16-aligned)

  __shared__ __align__(16) unsigned short Ks[64 * 128];    // [k][d], swizzled 16B chunks
  __shared__ __align__(16) unsigned short Vst[128 * 64];   // [d][k], swizzled
  __shared__ __align__(16) unsigned short Ps[128 * PS];    // [q_local][k]

  const int tid  = threadIdx.x;
  const int lane = tid & 63;
  const int w    = tid >> 6;
  const int quad = lane >> 4;
  const int l16  = lane & 15;

  // qt/bh swizzle: co-resident block pairs (id, id+256) get complementary qt.
  const int bx = blockIdx.x, by = blockIdx.y;
  const int qt = (by & 16) ? (15 - bx) : bx;
  const int bh = ((by & 15) << 1) | (by >> 4);
  const int qbase = qt * 128;
  const int nkt = 2 * qt + 2;

  const long headoff = (long)(bh >> 4) * S * D + (long)(bh & 15) * HD;
  const long vtoff   = (long)bh * HD * S;

  // staging address plan (per-tile add kbase)
  const unsigned short* gK[4]; unsigned short* lK[4];
  const unsigned short* gV[4]; unsigned short* lV[4];
#pragma unroll
  for (int i = 0; i < 4; ++i) {
    const int p = (w * 4 + i) * 64 + lane;          // 0..1023
    { const int r = p >> 4, cp = p & 15, c = cp ^ (r & 7);
      gK[i] = Kp + headoff + (long)r * D + c * 8;  lK[i] = &Ks[p * 8]; }
    { const int r = p >> 3, cp = p & 7, c = cp ^ (r & 7);
      gV[i] = Vt + vtoff + (long)r * S + c * 8;    lV[i] = &Vst[p * 8]; }
  }

  // Q fragments: strip s rows q = qbase + w*32 + s*16 + l16 (per-lane row)
  short8 aq[2][4];
  const int qrow[2] = {qbase + w * 32 + l16, qbase + w * 32 + 16 + l16};
#pragma unroll
  for (int s = 0; s < 2; ++s) {
    const unsigned short* qp = Q + headoff + (long)qrow[s] * D;
#pragma unroll
    for (int ks = 0; ks < 4; ++ks)
      aq[s][ks] = *(const short8*)(qp + ks * 32 + quad * 8);
  }

  floatx4 o_acc[2][8];
#pragma unroll
  for (int s = 0; s < 2; ++s)
#pragma unroll
    for (int t = 0; t < 8; ++t) o_acc[s][t] = (floatx4){0.f, 0.f, 0.f, 0.f};
  float m_i[2] = {-INFINITY, -INFINITY}, l_i[2] = {0.f, 0.f};

  const int lx7 = l16 & 7;

  for (int kt = 0; kt < nkt; ++kt) {
    const int kbase = kt * 64;
    __syncthreads();
#pragma unroll
    for (int i = 0; i < 4; ++i) gl_lds16(gK[i] + (long)kbase * D, lK[i]);
#pragma unroll
    for (int i = 0; i < 4; ++i) gl_lds16(gV[i] + kbase, lV[i]);
    __syncthreads();

    const bool do_mask = (kbase + 64 > qbase);

#pragma unroll
    for (int s = 0; s < 2; ++s) {
      // S^T tile: sc[nt] C-layout row = k_local = quad*4+rg (+nt*16), col = q = l16
      floatx4 sc[4];
#pragma unroll
      for (int nt = 0; nt < 4; ++nt) sc[nt] = (floatx4){0.f, 0.f, 0.f, 0.f};
#pragma unroll
      for (int nt = 0; nt < 4; ++nt) {
        const int krow = nt * 16 + l16;
#pragma unroll
        for (int ks = 0; ks < 4; ++ks) {
          const int cp = (ks * 4 + quad) ^ lx7;
          short8 kf = *(const short8*)&Ks[krow * 128 + cp * 8];
          sc[nt] = __builtin_amdgcn_mfma_f32_16x16x32_bf16(kf, aq[s][ks], sc[nt], 0, 0, 0);
        }
      }

      // mask + row-max (per-lane row = qrow[s])
      float sv[4][4];
      float rmax = -INFINITY;
      if (do_mask) {
        const int kg0 = kbase + quad * 4;
#pragma unroll
        for (int nt = 0; nt < 4; ++nt)
#pragma unroll
          for (int rg = 0; rg < 4; ++rg) {
            float v = sc[nt][rg];
            if (kg0 + nt * 16 + rg > qrow[s]) v = -INFINITY;
            sv[nt][rg] = v;
            rmax = fmaxf(rmax, v);
          }
      } else {
#pragma unroll
        for (int nt = 0; nt < 4; ++nt)
#pragma unroll
          for (int rg = 0; rg < 4; ++rg) {
            sv[nt][rg] = sc[nt][rg];
            rmax = fmaxf(rmax, sc[nt][rg]);
          }
      }
      rmax = fmaxf(rmax, __shfl_xor(rmax, 16));
      rmax = fmaxf(rmax, __shfl_xor(rmax, 32));

      const float mn = fmaxf(m_i[s], rmax);
      const float al = exp2f(m_i[s] - mn);
      m_i[s] = mn;

      float rsum = 0.f;
      const int qloc = w * 32 + s * 16 + l16;
#pragma unroll
      for (int nt = 0; nt < 4; ++nt) {
        short4b pk;
#pragma unroll
        for (int rg = 0; rg < 4; ++rg) {
          const float pe = exp2f(sv[nt][rg] - mn);
          rsum += pe;
          pk[rg] = f2bf(pe);
        }
        *(short4b*)&Ps[qloc * PS + nt * 16 + quad * 4] = pk;
      }
      rsum += __shfl_xor(rsum, 16);
      rsum += __shfl_xor(rsum, 32);
      l_i[s] = l_i[s] * al + rsum;

#pragma unroll
      for (int t = 0; t < 8; ++t)
#pragma unroll
        for (int rg = 0; rg < 4; ++rg) o_acc[s][t][rg] *= al;
    }

    // O^T += Vt_tile . P^T ; A-frag = Vst rows (d), B-frag = Ps rows (q) — wave-private
    short8 pf[2][2];
#pragma unroll
    for (int s = 0; s < 2; ++s) {
      const int qloc = w * 32 + s * 16 + l16;
#pragma unroll
      for (int ks = 0; ks < 2; ++ks)
        pf[s][ks] = *(const short8*)&Ps[qloc * PS + ks * 32 + quad * 8];
    }
#pragma unroll
    for (int t = 0; t < 8; ++t) {
      const int drow = t * 16 + l16;
#pragma unroll
      for (int ks = 0; ks < 2; ++ks) {
        const int cp = (ks * 4 + quad) ^ lx7;
        short8 vf = *(const short8*)&Vst[drow * 64 + cp * 8];
        o_acc[0][t] = __builtin_amdgcn_mfma_f32_16x16x32_bf16(vf, pf[0][ks], o_acc[0][t], 0, 0, 0);
        o_acc[1][t] = __builtin_amdgcn_mfma_f32_16x16x32_bf16(vf, pf[1][ks], o_acc[1][t], 0, 0, 0);
      }
    }
  }

  // epilogue: O^T C-layout: lane holds O[q = qrow[s]][d = t*16 + quad*4 + rg]
#pragma unroll
  for (int s = 0; s < 2; ++s) {
    const float rl = 1.0f / l_i[s];
    unsigned short* op = O + headoff + (long)qrow[s] * D;
#pragma unroll
    for (int t = 0; t < 8; ++t) {
      short4b ov;
#pragma unroll
      for (int rg = 0; rg < 4; ++rg) ov[rg] = f2bf(o_acc[s][t][rg] * rl);
      *(short4b*)(op + t * 16 + quad * 4) = ov;
    }
  }
}

extern "C" void kernel_launch(void* const* d_in, const int* in_sizes, int n_in,
                              void* d_out, int out_size, void* d_ws, size_t ws_size,
                              hipStream_t stream) {
  const float* query = (const float*)d_in[0];
  const float* key_  = (const float*)d_in[1];
  const float* value = (const float*)d_in[2];
  const float* Wq = (const float*)d_in[3];
  const float* bq = (const float*)d_in[4];
  const float* Wk = (const float*)d_in[5];
  const float* bk = (const float*)d_in[6];
  const float* Wv = (const float*)d_in[7];
  const float* bv = (const float*)d_in[8];
  const float* Wo = (const float*)d_in[9];
  const float* bo = (const float*)d_in[10];
  float* out = (float*)d_out;

  constexpr int Bz = 2, S = 2048, D = 2048;
  constexpr int M = Bz * S;
  constexpr long NELEM = (long)M * D;
  constexpr long WELEM = (long)D * D;

  const float qscale = 0.08838834764831845f * LOG2E;
  dim3 gridG(D / 128, M / 128);

  const size_t need_full = (size_t)(6 * NELEM + 4 * WELEM) * 2;

  if (ws_size >= need_full) {
    unsigned short* Qp  = (unsigned short*)d_ws;
    unsigned short* Kp  = Qp + NELEM;
    unsigned short* Vt  = Kp + NELEM;
    unsigned short* Xq  = Vt + NELEM;
    unsigned short* Xk  = Xq + NELEM;
    unsigned short* Xv  = Xk + NELEM;
    unsigned short* Wqb = Xv + NELEM;
    unsigned short* Wkb = Wqb + WELEM;
    unsigned short* Wvb = Wkb + WELEM;
    unsigned short* Wob = Wvb + WELEM;
    unsigned short* Oa  = Xq;

    cvt_k<<<dim3(NELEM / (8 * 256), 3), 256, 0, stream>>>(
        query, key_, value, value, Xq, Xk, Xv, Xv, (int)NELEM);
    cvt_k<<<dim3(WELEM / (8 * 256), 4), 256, 0, stream>>>(
        Wq, Wk, Wv, Wo, Wqb, Wkb, Wvb, Wob, (int)WELEM);

    gemm_bf16_k<true, false><<<gridG, 256, 0, stream>>>(Xq, Wqb, bq, Qp, M, D, D, qscale);
    gemm_bf16_k<true, false><<<gridG, 256, 0, stream>>>(Xk, Wkb, bk, Kp, M, D, D, 1.0f);
    gemm_bf16_k<true, true ><<<gridG, 256, 0, stream>>>(Xv, Wvb, bv, Vt, M, D, D, 1.0f);

    flash_attn_k<<<dim3(16, 32), 256, 0, stream>>>(Qp, Kp, Vt, Oa);

    gemm_bf16_k<false, false><<<gridG, 256, 0, stream>>>(Oa, Wob, bo, out, M, D, D, 1.0f);
  } else {
    unsigned short* Qp = (unsigned short*)d_ws;
    unsigned short* Kp = Qp + NELEM;
    unsigned short* Vt = Kp + NELEM;
    unsigned short* Oa = Vt + NELEM;

    gemm_bias_k<false, true, false><<<gridG, 256, 0, stream>>>(query, Wq, bq, Qp, M, D, D, qscale);
    gemm_bias_k<false, true, false><<<gridG, 256, 0, stream>>>(key_,  Wk, bk, Kp, M, D, D, 1.0f);
    gemm_bias_k<false, true, true ><<<gridG, 256, 0, stream>>>(value, Wv, bv, Vt, M, D, D, 1.0f);

    flash_attn_k<<<dim3(16, 32), 256, 0, stream>>>(Qp, Kp, Vt, Oa);

    gemm_bias_k<true, false, false><<<gridG, 256, 0, stream>>>(Oa, Wo, bo, out, M, D, D, 1.0f);
  }
}

// Round 5
// 467.690 us; speedup vs baseline: 2.3745x; 1.1206x over previous
//
#include <hip/hip_runtime.h>
#include <hip/hip_bf16.h>

// B=2, S=2048, D=2048, H=16, HD=128, causal MHA with 4 linear projections.
// cvt fp32->bf16 -> 3 bf16 GEMMs (V transposed per head) -> flash attn (transposed
// score layout, per-lane softmax rows, uniform-balance paired q-tiles) -> out-proj GEMM.

#define LOG2E 1.44269504088896340736f

typedef __attribute__((ext_vector_type(8))) short short8;    // 8 x bf16
typedef __attribute__((ext_vector_type(4))) short short4b;   // 4 x bf16
typedef __attribute__((ext_vector_type(4))) float floatx4;   // MFMA acc

__device__ __forceinline__ short f2bf(float f) {
  unsigned int u = __builtin_bit_cast(unsigned int, f);
  u += 0x7FFFu + ((u >> 16) & 1u);  // RNE
  return (short)(u >> 16);
}

__device__ __forceinline__ short4b pack4bf(float a, float b, float c, float d) {
  __hip_bfloat162 lo = __float22bfloat162_rn(float2{a, b});
  __hip_bfloat162 hi = __float22bfloat162_rn(float2{c, d});
  short4b r;
  r[0] = __builtin_bit_cast(short, lo.x); r[1] = __builtin_bit_cast(short, lo.y);
  r[2] = __builtin_bit_cast(short, hi.x); r[3] = __builtin_bit_cast(short, hi.y);
  return r;
}

__device__ __forceinline__ void gl_lds16(const void* g, void* l) {
  __builtin_amdgcn_global_load_lds(
      (const __attribute__((address_space(1))) unsigned int*)g,
      (__attribute__((address_space(3))) unsigned int*)l, 16, 0, 0);
}

// ---------------- fp32 -> bf16 conversion (up to 4 arrays per launch) -------
__global__ __launch_bounds__(256) void cvt_k(
    const float* __restrict__ s0, const float* __restrict__ s1,
    const float* __restrict__ s2, const float* __restrict__ s3,
    unsigned short* __restrict__ d0, unsigned short* __restrict__ d1,
    unsigned short* __restrict__ d2, unsigned short* __restrict__ d3, int n)
{
  const float* s; unsigned short* d;
  switch (blockIdx.y) {
    case 0: s = s0; d = d0; break;
    case 1: s = s1; d = d1; break;
    case 2: s = s2; d = d2; break;
    default: s = s3; d = d3; break;
  }
  const int i = (blockIdx.x * 256 + threadIdx.x) * 8;
  if (i >= n) return;
  float4 a = *(const float4*)(s + i);
  float4 b = *(const float4*)(s + i + 4);
  short8 v = (short8){f2bf(a.x), f2bf(a.y), f2bf(a.z), f2bf(a.w),
                      f2bf(b.x), f2bf(b.y), f2bf(b.z), f2bf(b.w)};
  *(short8*)(d + i) = v;
}

// ---------------- bf16 GEMM via global_load_lds + XOR-swizzled LDS ----------
template<bool OUT_BF16, bool VT_OUT>
__global__ __launch_bounds__(256, 2) void gemm_bf16_k(
    const unsigned short* __restrict__ A, const unsigned short* __restrict__ Bt,
    const float* __restrict__ bias, void* __restrict__ Cptr,
    int M, int N, int K, float alpha)
{
  __shared__ __align__(16) unsigned short smem[VT_OUT ? 128 * 136 : 128 * 64];
  unsigned short* As = smem;             // [128][32] swizzled
  unsigned short* Bs = smem + 128 * 32;  // [128][32] swizzled

  const int tid  = threadIdx.x;
  const int lane = tid & 63;
  const int wave = tid >> 6;
  const int quad = lane >> 4;
  const int l16  = lane & 15;
  const int wr   = wave >> 1, wc = wave & 1;
  const long bm  = (long)blockIdx.y * 128;
  const long bn  = (long)blockIdx.x * 128;

  const unsigned short* agp[2]; const unsigned short* bgp[2];
  unsigned short* alp[2]; unsigned short* blp[2];
#pragma unroll
  for (int j = 0; j < 2; ++j) {
    const int p = (wave * 2 + j) * 64 + lane;  // chunk slot 0..511
    const int r = p >> 2, cs = p & 3;
    const int cg = cs ^ ((r >> 1) & 3);
    agp[j] = A  + (bm + r) * (long)K + cg * 8;
    bgp[j] = Bt + (bn + r) * (long)K + cg * 8;
    alp[j] = As + p * 8;
    blp[j] = Bs + p * 8;
  }

  floatx4 acc[4][4];
#pragma unroll
  for (int i = 0; i < 4; ++i)
#pragma unroll
    for (int j = 0; j < 4; ++j) acc[i][j] = (floatx4){0.f, 0.f, 0.f, 0.f};

  const int coff = (quad ^ ((l16 >> 1) & 3)) * 8;

  for (int k0 = 0; k0 < K; k0 += 32) {
    __syncthreads();
    gl_lds16(agp[0] + k0, alp[0]);
    gl_lds16(agp[1] + k0, alp[1]);
    gl_lds16(bgp[0] + k0, blp[0]);
    gl_lds16(bgp[1] + k0, blp[1]);
    __syncthreads();

    short8 af[4], bf[4];
#pragma unroll
    for (int t = 0; t < 4; ++t) {
      af[t] = *(const short8*)&As[(wr * 64 + t * 16 + l16) * 32 + coff];
      bf[t] = *(const short8*)&Bs[(wc * 64 + t * 16 + l16) * 32 + coff];
    }
#pragma unroll
    for (int mt = 0; mt < 4; ++mt)
#pragma unroll
      for (int nt = 0; nt < 4; ++nt)
        acc[mt][nt] = __builtin_amdgcn_mfma_f32_16x16x32_bf16(af[mt], bf[nt], acc[mt][nt], 0, 0, 0);
  }

  if (VT_OUT) {
    __syncthreads();
    unsigned short* Ct = smem;  // [128 col][136]
#pragma unroll
    for (int nt = 0; nt < 4; ++nt) {
      const long col = bn + wc * 64 + nt * 16 + l16;
      const float bval = bias[col];
      const int col_l = wc * 64 + nt * 16 + l16;
#pragma unroll
      for (int mt = 0; mt < 4; ++mt) {
        const int row_l = wr * 64 + mt * 16 + quad * 4;
#pragma unroll
        for (int rg = 0; rg < 4; ++rg)
          Ct[col_l * 136 + row_l + rg] = (unsigned short)f2bf((acc[mt][nt][rg] + bval) * alpha);
      }
    }
    __syncthreads();
    const int b  = (int)(bm >> 11);
    const int s0 = (int)(bm & 2047);
    const int r    = tid >> 1;
    const int half = tid & 1;
    unsigned short* dst = (unsigned short*)Cptr +
        ((long)(b * 16 + blockIdx.x) * 128 + r) * 2048 + s0 + half * 64;
    const unsigned short* src = &Ct[r * 136 + half * 64];
#pragma unroll
    for (int c = 0; c < 8; ++c)
      *(uint4*)(dst + c * 8) = *(const uint4*)(src + c * 8);
  } else {
#pragma unroll
    for (int nt = 0; nt < 4; ++nt) {
      const long col = bn + wc * 64 + nt * 16 + l16;
      const float bval = bias[col];
#pragma unroll
      for (int mt = 0; mt < 4; ++mt) {
#pragma unroll
        for (int rg = 0; rg < 4; ++rg) {
          const long row = bm + wr * 64 + mt * 16 + quad * 4 + rg;
          const float v = (acc[mt][nt][rg] + bval) * alpha;
          if (OUT_BF16) ((unsigned short*)Cptr)[row * (long)N + col] = (unsigned short)f2bf(v);
          else          ((float*)Cptr)[row * (long)N + col] = v;
        }
      }
    }
  }
}

// ---------------- fallback GEMM (fp32 operands) -----------------------------
template<bool A_BF16, bool OUT_BF16, bool VT_OUT>
__global__ __launch_bounds__(256, 2) void gemm_bias_k(
    const void* __restrict__ Aptr, const float* __restrict__ Bt,
    const float* __restrict__ bias, void* __restrict__ Cptr,
    int M, int N, int K, float alpha)
{
  __shared__ __align__(16) unsigned short smem[128 * 136];
  unsigned short* As = smem;
  unsigned short* Bs = smem + 128 * 40;

  const int tid  = threadIdx.x;
  const int lane = tid & 63;
  const int wave = tid >> 6;
  const int quad = lane >> 4;
  const int l16  = lane & 15;
  const int wr   = wave >> 1, wc = wave & 1;
  const long bm  = (long)blockIdx.y * 128;
  const long bn  = (long)blockIdx.x * 128;

  floatx4 acc[4][4];
#pragma unroll
  for (int i = 0; i < 4; ++i)
#pragma unroll
    for (int j = 0; j < 4; ++j) acc[i][j] = (floatx4){0.f, 0.f, 0.f, 0.f};

  const int srow = tid >> 2;
  const int cc   = tid & 3;

  for (int k0 = 0; k0 < K; k0 += 32) {
    __syncthreads();
#pragma unroll
    for (int r = 0; r < 2; ++r) {
      const int row = srow + r * 64;
      short8 av, bv;
      if (A_BF16) {
        av = *(const short8*)((const unsigned short*)Aptr + (bm + row) * (long)K + k0 + cc * 8);
      } else {
        const float* ap = (const float*)Aptr + (bm + row) * (long)K + k0 + cc * 8;
        float4 f0 = *(const float4*)ap;
        float4 f1 = *(const float4*)(ap + 4);
        av = (short8){f2bf(f0.x), f2bf(f0.y), f2bf(f0.z), f2bf(f0.w),
                      f2bf(f1.x), f2bf(f1.y), f2bf(f1.z), f2bf(f1.w)};
      }
      {
        const float* bp = Bt + (bn + row) * (long)K + k0 + cc * 8;
        float4 g0 = *(const float4*)bp;
        float4 g1 = *(const float4*)(bp + 4);
        bv = (short8){f2bf(g0.x), f2bf(g0.y), f2bf(g0.z), f2bf(g0.w),
                      f2bf(g1.x), f2bf(g1.y), f2bf(g1.z), f2bf(g1.w)};
      }
      *(short8*)&As[row * 40 + cc * 8] = av;
      *(short8*)&Bs[row * 40 + cc * 8] = bv;
    }
    __syncthreads();

    short8 af[4], bf[4];
#pragma unroll
    for (int t = 0; t < 4; ++t) {
      af[t] = *(const short8*)&As[(wr * 64 + t * 16 + l16) * 40 + quad * 8];
      bf[t] = *(const short8*)&Bs[(wc * 64 + t * 16 + l16) * 40 + quad * 8];
    }
#pragma unroll
    for (int mt = 0; mt < 4; ++mt)
#pragma unroll
      for (int nt = 0; nt < 4; ++nt)
        acc[mt][nt] = __builtin_amdgcn_mfma_f32_16x16x32_bf16(af[mt], bf[nt], acc[mt][nt], 0, 0, 0);
  }

  if (VT_OUT) {
    __syncthreads();
    unsigned short* Ct = smem;
#pragma unroll
    for (int nt = 0; nt < 4; ++nt) {
      const long col = bn + wc * 64 + nt * 16 + l16;
      const float bval = bias[col];
      const int col_l = wc * 64 + nt * 16 + l16;
#pragma unroll
      for (int mt = 0; mt < 4; ++mt) {
        const int row_l = wr * 64 + mt * 16 + quad * 4;
#pragma unroll
        for (int rg = 0; rg < 4; ++rg)
          Ct[col_l * 136 + row_l + rg] = (unsigned short)f2bf((acc[mt][nt][rg] + bval) * alpha);
      }
    }
    __syncthreads();
    const int b  = (int)(bm >> 11);
    const int s0 = (int)(bm & 2047);
    const int r    = tid >> 1;
    const int half = tid & 1;
    unsigned short* dst = (unsigned short*)Cptr +
        ((long)(b * 16 + blockIdx.x) * 128 + r) * 2048 + s0 + half * 64;
    const unsigned short* src = &Ct[r * 136 + half * 64];
#pragma unroll
    for (int c = 0; c < 8; ++c)
      *(uint4*)(dst + c * 8) = *(const uint4*)(src + c * 8);
  } else {
#pragma unroll
    for (int nt = 0; nt < 4; ++nt) {
      const long col = bn + wc * 64 + nt * 16 + l16;
      const float bval = bias[col];
#pragma unroll
      for (int mt = 0; mt < 4; ++mt) {
#pragma unroll
        for (int rg = 0; rg < 4; ++rg) {
          const long row = bm + wr * 64 + mt * 16 + quad * 4 + rg;
          const float v = (acc[mt][nt][rg] + bval) * alpha;
          if (OUT_BF16) ((unsigned short*)Cptr)[row * (long)N + col] = (unsigned short)f2bf(v);
          else          ((float*)Cptr)[row * (long)N + col] = v;
        }
      }
    }
  }
}

// ---------------- flash attention, transposed scores + uniform pairing ------
// Q,K,O: bf16 [B,S,H,HD] (Q pre-scaled by SCALE*LOG2E). Vt: bf16 [B*H][HD][S].
// Block 256 thr = 4 waves; processes q-tiles {bx, 31-bx} (64 rows each)
// SEQUENTIALLY -> uniform 33 k-tile-iters per block; grid 512 = 2 blocks/CU,
// whose barriers interleave (implicit double-buffer). Wave owns 16 q-rows;
// scores S^T = K.Q^T (lane owns one q-row: softmax = in-lane + 2 shuffles);
// O^T = Vt.P^T. K/V staged via global_load_lds into XOR-swizzled LDS.
__global__ __launch_bounds__(256, 2) void flash_attn_k(
    const unsigned short* __restrict__ Q,
    const unsigned short* __restrict__ Kp,
    const unsigned short* __restrict__ Vt,
    unsigned short* __restrict__ O)
{
  constexpr int S = 2048, D = 2048, HD = 128;
  constexpr int PS = 72;  // Ps stride (shorts)

  __shared__ __align__(16) unsigned short Ks[64 * 128];    // [k][d], swizzled 16B chunks
  __shared__ __align__(16) unsigned short Vst[128 * 64];   // [d][k], swizzled
  __shared__ __align__(16) unsigned short Ps[64 * PS];     // [q_local][k]

  const int tid  = threadIdx.x;
  const int lane = tid & 63;
  const int w    = tid >> 6;
  const int quad = lane >> 4;
  const int l16  = lane & 15;
  const int lx7  = l16 & 7;

  const int bh = blockIdx.y;
  const long headoff = (long)(bh >> 4) * S * D + (long)(bh & 15) * HD;
  const long vtoff   = (long)bh * HD * S;

  // staging plan (per-tile: add kbase)
  const unsigned short* gK[4]; unsigned short* lK[4];
  const unsigned short* gV[4]; unsigned short* lV[4];
#pragma unroll
  for (int i = 0; i < 4; ++i) {
    const int p = (w * 4 + i) * 64 + lane;          // 0..1023
    { const int r = p >> 4, cp = p & 15, c = cp ^ (r & 7);
      gK[i] = Kp + headoff + (long)r * D + c * 8;  lK[i] = &Ks[p * 8]; }
    { const int r = p >> 3, cp = p & 7, c = cp ^ (r & 7);
      gV[i] = Vt + vtoff + (long)r * S + c * 8;    lV[i] = &Vst[p * 8]; }
  }

#pragma unroll 1
  for (int half = 0; half < 2; ++half) {
    const int qt = half ? (31 - (int)blockIdx.x) : (int)blockIdx.x;
    const int qbase = qt * 64;
    const int qrow  = qbase + w * 16 + l16;   // this lane's q row
    const int qloc  = w * 16 + l16;

    // Q fragments (B-operand layout: n = l16 = own row, k-chunks of 32)
    short8 aq[4];
    {
      const unsigned short* qp = Q + headoff + (long)qrow * D;
#pragma unroll
      for (int ks = 0; ks < 4; ++ks)
        aq[ks] = *(const short8*)(qp + ks * 32 + quad * 8);
    }

    floatx4 o_acc[8];
#pragma unroll
    for (int t = 0; t < 8; ++t) o_acc[t] = (floatx4){0.f, 0.f, 0.f, 0.f};
    float m_i = -INFINITY, l_i = 0.f;

    for (int kt = 0; kt <= qt; ++kt) {
      const int kbase = kt * 64;
      __syncthreads();
#pragma unroll
      for (int i = 0; i < 4; ++i) gl_lds16(gK[i] + (long)kbase * D, lK[i]);
#pragma unroll
      for (int i = 0; i < 4; ++i) gl_lds16(gV[i] + kbase, lV[i]);
      __syncthreads();

      // S^T tile: sc[nt] D-layout: k_local = nt*16 + quad*4 + rg, q-col = l16
      floatx4 sc[4];
#pragma unroll
      for (int nt = 0; nt < 4; ++nt) sc[nt] = (floatx4){0.f, 0.f, 0.f, 0.f};
#pragma unroll
      for (int nt = 0; nt < 4; ++nt) {
        const int krow = nt * 16 + l16;
#pragma unroll
        for (int ks = 0; ks < 4; ++ks) {
          const int cp = (ks * 4 + quad) ^ lx7;
          short8 kf = *(const short8*)&Ks[krow * 128 + cp * 8];
          sc[nt] = __builtin_amdgcn_mfma_f32_16x16x32_bf16(kf, aq[ks], sc[nt], 0, 0, 0);
        }
      }

      float sv[4][4];
      float rmax = -INFINITY;
      if (kt == qt) {  // diagonal tile only: causal mask
        const int kg0 = kbase + quad * 4;
#pragma unroll
        for (int nt = 0; nt < 4; ++nt)
#pragma unroll
          for (int rg = 0; rg < 4; ++rg) {
            float v = sc[nt][rg];
            if (kg0 + nt * 16 + rg > qrow) v = -INFINITY;
            sv[nt][rg] = v;
            rmax = fmaxf(rmax, v);
          }
      } else {
#pragma unroll
        for (int nt = 0; nt < 4; ++nt)
#pragma unroll
          for (int rg = 0; rg < 4; ++rg) {
            sv[nt][rg] = sc[nt][rg];
            rmax = fmaxf(rmax, sc[nt][rg]);
          }
      }
      rmax = fmaxf(rmax, __shfl_xor(rmax, 16));
      rmax = fmaxf(rmax, __shfl_xor(rmax, 32));

      const float mn = fmaxf(m_i, rmax);
      const float al = exp2f(m_i - mn);
      m_i = mn;

      float rsum = 0.f;
#pragma unroll
      for (int nt = 0; nt < 4; ++nt) {
        float p0 = exp2f(sv[nt][0] - mn), p1 = exp2f(sv[nt][1] - mn);
        float p2 = exp2f(sv[nt][2] - mn), p3 = exp2f(sv[nt][3] - mn);
        rsum += (p0 + p1) + (p2 + p3);
        *(short4b*)&Ps[qloc * PS + nt * 16 + quad * 4] = pack4bf(p0, p1, p2, p3);
      }
      rsum += __shfl_xor(rsum, 16);
      rsum += __shfl_xor(rsum, 32);
      l_i = l_i * al + rsum;

      if (__any(al != 1.0f)) {
#pragma unroll
        for (int t = 0; t < 8; ++t)
#pragma unroll
          for (int rg = 0; rg < 4; ++rg) o_acc[t][rg] *= al;
      }

      // P fragments (wave-private region of Ps: same-wave write->read, in-order DS)
      short8 pf[2];
#pragma unroll
      for (int ks = 0; ks < 2; ++ks)
        pf[ks] = *(const short8*)&Ps[qloc * PS + ks * 32 + quad * 8];

      // O^T += Vt_tile . P^T
#pragma unroll
      for (int t = 0; t < 8; ++t) {
        const int drow = t * 16 + l16;
#pragma unroll
        for (int ks = 0; ks < 2; ++ks) {
          const int cp = (ks * 4 + quad) ^ lx7;
          short8 vf = *(const short8*)&Vst[drow * 64 + cp * 8];
          o_acc[t] = __builtin_amdgcn_mfma_f32_16x16x32_bf16(vf, pf[ks], o_acc[t], 0, 0, 0);
        }
      }
    }

    // epilogue: lane holds O[qrow][d = t*16 + quad*4 + rg]
    const float rl = 1.0f / l_i;
    unsigned short* op = O + headoff + (long)qrow * D;
#pragma unroll
    for (int t = 0; t < 8; ++t) {
      *(short4b*)(op + t * 16 + quad * 4) =
          pack4bf(o_acc[t][0] * rl, o_acc[t][1] * rl, o_acc[t][2] * rl, o_acc[t][3] * rl);
    }
  }
}

extern "C" void kernel_launch(void* const* d_in, const int* in_sizes, int n_in,
                              void* d_out, int out_size, void* d_ws, size_t ws_size,
                              hipStream_t stream) {
  const float* query = (const float*)d_in[0];
  const float* key_  = (const float*)d_in[1];
  const float* value = (const float*)d_in[2];
  const float* Wq = (const float*)d_in[3];
  const float* bq = (const float*)d_in[4];
  const float* Wk = (const float*)d_in[5];
  const float* bk = (const float*)d_in[6];
  const float* Wv = (const float*)d_in[7];
  const float* bv = (const float*)d_in[8];
  const float* Wo = (const float*)d_in[9];
  const float* bo = (const float*)d_in[10];
  float* out = (float*)d_out;

  constexpr int Bz = 2, S = 2048, D = 2048;
  constexpr int M = Bz * S;
  constexpr long NELEM = (long)M * D;
  constexpr long WELEM = (long)D * D;

  const float qscale = 0.08838834764831845f * LOG2E;
  dim3 gridG(D / 128, M / 128);

  const size_t need_full = (size_t)(6 * NELEM + 4 * WELEM) * 2;

  if (ws_size >= need_full) {
    unsigned short* Qp  = (unsigned short*)d_ws;
    unsigned short* Kp  = Qp + NELEM;
    unsigned short* Vt  = Kp + NELEM;
    unsigned short* Xq  = Vt + NELEM;
    unsigned short* Xk  = Xq + NELEM;
    unsigned short* Xv  = Xk + NELEM;
    unsigned short* Wqb = Xv + NELEM;
    unsigned short* Wkb = Wqb + WELEM;
    unsigned short* Wvb = Wkb + WELEM;
    unsigned short* Wob = Wvb + WELEM;
    unsigned short* Oa  = Xq;

    cvt_k<<<dim3(NELEM / (8 * 256), 3), 256, 0, stream>>>(
        query, key_, value, value, Xq, Xk, Xv, Xv, (int)NELEM);
    cvt_k<<<dim3(WELEM / (8 * 256), 4), 256, 0, stream>>>(
        Wq, Wk, Wv, Wo, Wqb, Wkb, Wvb, Wob, (int)WELEM);

    gemm_bf16_k<true, false><<<gridG, 256, 0, stream>>>(Xq, Wqb, bq, Qp, M, D, D, qscale);
    gemm_bf16_k<true, false><<<gridG, 256, 0, stream>>>(Xk, Wkb, bk, Kp, M, D, D, 1.0f);
    gemm_bf16_k<true, true ><<<gridG, 256, 0, stream>>>(Xv, Wvb, bv, Vt, M, D, D, 1.0f);

    flash_attn_k<<<dim3(16, 32), 256, 0, stream>>>(Qp, Kp, Vt, Oa);

    gemm_bf16_k<false, false><<<gridG, 256, 0, stream>>>(Oa, Wob, bo, out, M, D, D, 1.0f);
  } else {
    unsigned short* Qp = (unsigned short*)d_ws;
    unsigned short* Kp = Qp + NELEM;
    unsigned short* Vt = Kp + NELEM;
    unsigned short* Oa = Vt + NELEM;

    gemm_bias_k<false, true, false><<<gridG, 256, 0, stream>>>(query, Wq, bq, Qp, M, D, D, qscale);
    gemm_bias_k<false, true, false><<<gridG, 256, 0, stream>>>(key_,  Wk, bk, Kp, M, D, D, 1.0f);
    gemm_bias_k<false, true, true ><<<gridG, 256, 0, stream>>>(value, Wv, bv, Vt, M, D, D, 1.0f);

    flash_attn_k<<<dim3(16, 32), 256, 0, stream>>>(Qp, Kp, Vt, Oa);

    gemm_bias_k<true, false, false><<<gridG, 256, 0, stream>>>(Oa, Wo, bo, out, M, D, D, 1.0f);
  }
}